// Round 1
// baseline (409.955 us; speedup 1.0000x reference)
//
#include <hip/hip_runtime.h>

typedef unsigned short u16;
typedef __attribute__((ext_vector_type(4))) float floatx4;
typedef __attribute__((ext_vector_type(8))) short short8;

#define TTOK 2048
#define MAXROWS 5120   // 4096 slots + 8*128 padding
#define MAXMT 40

__device__ __forceinline__ u16 f2bf(float f) {
    union { float f; unsigned u; } v; v.f = f;
    unsigned r = v.u + 0x7FFF + ((v.u >> 16) & 1);
    return (u16)(r >> 16);
}
__device__ __forceinline__ float silu_f(float x) { return x / (1.f + __expf(-x)); }

__device__ __forceinline__ void gl_lds16(const void* g, void* l) {
    __builtin_amdgcn_global_load_lds(
        (__attribute__((address_space(1))) unsigned int*)g,
        (__attribute__((address_space(3))) unsigned int*)l, 16, 0, 0);
}

// ---- convert all fp32 weights (+x) to bf16 into workspace, one pass ----
// segments (in float4 units): w1(2097152)->W13 interleave, w3(2097152)->W13,
// w2(2097152)->W2b, sw1(524288)->S12, sw2(524288)->S12+off, sw3(524288)->S3b,
// x(524288)->Xb.  total 8388608 float4
__global__ void conv_all(const float* __restrict__ w1, const float* __restrict__ w2,
                         const float* __restrict__ w3, const float* __restrict__ sw1,
                         const float* __restrict__ sw2, const float* __restrict__ sw3,
                         const float* __restrict__ x,
                         u16* __restrict__ W13, u16* __restrict__ W2b,
                         u16* __restrict__ S12, u16* __restrict__ S3b,
                         u16* __restrict__ Xb) {
    long j = (long)blockIdx.x * 256 + threadIdx.x;
    const float* src; u16* dst; long d;
    if (j < 2097152) {                       // w1 -> W13 rows [0,1024) of each expert
        long e = j >> 18; src = w1; dst = W13; d = j + (e << 18);
    } else if ((j -= 2097152) < 2097152) {   // w3 -> W13 rows [1024,2048)
        long e = j >> 18; src = w3; dst = W13; d = j + (e << 18) + 262144;
    } else if ((j -= 2097152) < 2097152) { src = w2;  dst = W2b; d = j; }
    else if ((j -= 2097152) < 524288)    { src = sw1; dst = S12; d = j; }
    else if ((j -= 524288) < 524288)     { src = sw2; dst = S12; d = j + 524288; }
    else if ((j -= 524288) < 524288)     { src = sw3; dst = S3b; d = j; }
    else { j -= 524288; src = x; dst = Xb; d = j; }
    float4 v = ((const float4*)src)[j];
    ushort4 o; o.x = f2bf(v.x); o.y = f2bf(v.y); o.z = f2bf(v.z); o.w = f2bf(v.w);
    ((ushort4*)dst)[d] = o;
}

// ---- gate: logits -> softmax -> top2 (matches lax.top_k tie order) ----
__global__ void gate_k(const float* __restrict__ x, const float* __restrict__ gw,
                       int* __restrict__ idxA, float* __restrict__ wA,
                       int* __restrict__ counts) {
    int w = threadIdx.x >> 6, lane = threadIdx.x & 63;
    int t = blockIdx.x * 4 + w;
    const float* xr = x + (size_t)t * 1024;
    float acc[8];
#pragma unroll
    for (int e = 0; e < 8; e++) acc[e] = 0.f;
#pragma unroll
    for (int i = 0; i < 16; i++) {
        float xv = xr[lane + (i << 6)];
#pragma unroll
        for (int e = 0; e < 8; e++) acc[e] += xv * gw[e * 1024 + lane + (i << 6)];
    }
#pragma unroll
    for (int e = 0; e < 8; e++)
        for (int off = 32; off > 0; off >>= 1) acc[e] += __shfl_xor(acc[e], off);
    if (lane == 0) {
        float m = acc[0];
#pragma unroll
        for (int e = 1; e < 8; e++) m = fmaxf(m, acc[e]);
        float p[8], s = 0.f;
#pragma unroll
        for (int e = 0; e < 8; e++) { p[e] = __expf(acc[e] - m); s += p[e]; }
        float inv = 1.f / s;
#pragma unroll
        for (int e = 0; e < 8; e++) p[e] *= inv;
        int i0 = 0;
#pragma unroll
        for (int e = 1; e < 8; e++) if (p[e] > p[i0]) i0 = e;
        int i1 = (i0 == 0) ? 1 : 0;
        for (int e = i1 + 1; e < 8; e++) if (e != i0 && p[e] > p[i1]) i1 = e;
        idxA[2 * t] = i0; idxA[2 * t + 1] = i1;
        wA[2 * t] = p[i0]; wA[2 * t + 1] = p[i1];
        atomicAdd(&counts[i0], 1); atomicAdd(&counts[i1], 1);
    }
}

__global__ void scan_k(const int* __restrict__ counts, int* __restrict__ baserow,
                       int* __restrict__ tileexp, int* __restrict__ ntiles) {
    if (threadIdx.x == 0) {
        int tot = 0;
        for (int e = 0; e < 8; e++) {
            baserow[e] = tot * 128;
            int te = (counts[e] + 127) >> 7;
            for (int j = 0; j < te; j++) tileexp[tot + j] = e;
            tot += te;
        }
        ntiles[0] = tot;
    }
}

__global__ void scatter_k(const int* __restrict__ idxA, const int* __restrict__ baserow,
                          int* __restrict__ cursor, int* __restrict__ slot_of) {
    int s = blockIdx.x * 256 + threadIdx.x;
    if (s >= 4096) return;
    int e = idxA[s];
    int pos = atomicAdd(&cursor[e], 1);
    slot_of[s] = baserow[e] + pos;
}

// xs[slot] = x[t] * weight  (bf16), one block per token-slot
__global__ void build_xs(const float* __restrict__ x, const float* __restrict__ wA,
                         const int* __restrict__ slot_of, u16* __restrict__ XS) {
    int s = blockIdx.x, i = threadIdx.x;
    int t = s >> 1; float w = wA[s]; int slot = slot_of[s];
    float4 v = ((const float4*)(x + (size_t)t * 1024))[i];
    ushort4 o; o.x = f2bf(v.x * w); o.y = f2bf(v.y * w); o.z = f2bf(v.z * w); o.w = f2bf(v.w * w);
    ((ushort4*)(XS + (size_t)slot * 1024))[i] = o;
}

// G[t][c] = bf16(silu(U)*V) from UV (T x 4096 fp32), processed in float4 units
__global__ void comb_g(const float* __restrict__ UV, u16* __restrict__ G) {
    int i = blockIdx.x * 256 + threadIdx.x;  // 2048*512
    int t = i >> 9, c4 = i & 511;
    float4 u = ((const float4*)UV)[(size_t)t * 1024 + c4];
    float4 v = ((const float4*)UV)[(size_t)t * 1024 + 512 + c4];
    ushort4 o;
    o.x = f2bf(silu_f(u.x) * v.x); o.y = f2bf(silu_f(u.y) * v.y);
    o.z = f2bf(silu_f(u.z) * v.z); o.w = f2bf(silu_f(u.w) * v.w);
    ((ushort4*)G)[(size_t)t * 512 + c4] = o;
}

// ---- m97-style bf16 TN GEMM, 128x128 tile, BK=32, fused epilogues ----
// MODE 0: routed stage A: out cols<1024 -> H=bf16(silu(acc+b1)); cols>=1024 -> X3f=acc+b3
// MODE 1: routed stage B: Y2f = (acc+b2) * X3f
// MODE 2: shared stage A: UVf = acc
// MODE 3: shared stage B: out = acc + Y2f[slot0] + Y2f[slot1]
template <int MODE>
__global__ __launch_bounds__(256) void gemm_k(
    const u16* __restrict__ A, const u16* __restrict__ Bw,
    const float* __restrict__ biasA, const float* __restrict__ biasB,
    const float* __restrict__ aux, float* __restrict__ outf, u16* __restrict__ outh,
    const int* __restrict__ tileexp, const int* __restrict__ ntiles,
    const int* __restrict__ slot_of, int lda, int K, int N) {
    __shared__ u16 ldsA[128 * 32];
    __shared__ u16 ldsB[128 * 32];

    int mt = blockIdx.x;
    int e = 0;
    if (MODE == 0 || MODE == 1) {
        if (mt >= ntiles[0]) return;
        e = tileexp[mt];
    }
    const u16* Bp = Bw + (size_t)e * N * K;
    int m0 = mt * 128, n0 = blockIdx.y * 128;
    int tid = threadIdx.x, w = tid >> 6, lane = tid & 63;
    int wm = w >> 1, wn = w & 1;

    floatx4 acc[4][4];
#pragma unroll
    for (int i = 0; i < 4; i++)
#pragma unroll
        for (int j = 0; j < 4; j++) { floatx4 z = {0.f, 0.f, 0.f, 0.f}; acc[i][j] = z; }

    int rloc = lane >> 2, clds = lane & 3, q = lane >> 4, l15 = lane & 15;

    for (int k0 = 0; k0 < K; k0 += 32) {
#pragma unroll
        for (int t = 0; t < 2; t++) {
            int r = (w << 4) + (t << 6) + rloc;  // tile row 0..127
            int cg = clds ^ ((r >> 1) & 3);      // xor-swizzled granule
            gl_lds16(A + (size_t)(m0 + r) * lda + k0 + (cg << 3),
                     &ldsA[((w << 4) + (t << 6)) * 32]);
            gl_lds16(Bp + (size_t)(n0 + r) * K + k0 + (cg << 3),
                     &ldsB[((w << 4) + (t << 6)) * 32]);
        }
        __syncthreads();  // drains vmcnt for global_load_lds

        short8 af[4], bf[4];
#pragma unroll
        for (int i = 0; i < 4; i++) {
            int rr = (wm << 6) + (i << 4) + l15;
            int c = q ^ ((rr >> 1) & 3);
            af[i] = *(const short8*)&ldsA[rr * 32 + (c << 3)];
        }
#pragma unroll
        for (int j = 0; j < 4; j++) {
            int rr = (wn << 6) + (j << 4) + l15;
            int c = q ^ ((rr >> 1) & 3);
            bf[j] = *(const short8*)&ldsB[rr * 32 + (c << 3)];
        }
#pragma unroll
        for (int i = 0; i < 4; i++)
#pragma unroll
            for (int j = 0; j < 4; j++)
                acc[i][j] = __builtin_amdgcn_mfma_f32_16x16x32_bf16(af[i], bf[j], acc[i][j], 0, 0, 0);
        __syncthreads();
    }

    // epilogue: element (row,col): col=lane&15, row=(lane>>4)*4+reg  [m89/m91]
#pragma unroll
    for (int i = 0; i < 4; i++) {
        int rowb = m0 + (wm << 6) + (i << 4) + (q << 2);
#pragma unroll
        for (int j = 0; j < 4; j++) {
            int col = n0 + (wn << 6) + (j << 4) + l15;
#pragma unroll
            for (int r = 0; r < 4; r++) {
                float v = acc[i][j][r];
                int rw = rowb + r;
                if (MODE == 0) {
                    if (col < 1024) {
                        float h = silu_f(v + biasA[e * 1024 + col]);
                        outh[(size_t)rw * 1024 + col] = f2bf(h);
                    } else {
                        int c2 = col - 1024;
                        outf[(size_t)rw * 1024 + c2] = v + biasB[e * 1024 + c2];
                    }
                } else if (MODE == 1) {
                    float y = (v + biasA[e * 1024 + col]) * aux[(size_t)rw * 1024 + col];
                    outf[(size_t)rw * 1024 + col] = y;
                } else if (MODE == 2) {
                    outf[(size_t)rw * 4096 + col] = v;
                } else {
                    float y = aux[(size_t)slot_of[rw * 2] * 1024 + col] +
                              aux[(size_t)slot_of[rw * 2 + 1] * 1024 + col];
                    outf[(size_t)rw * 1024 + col] = v + y;
                }
            }
        }
    }
}

extern "C" void kernel_launch(void* const* d_in, const int* in_sizes, int n_in,
                              void* d_out, int out_size, void* d_ws, size_t ws_size,
                              hipStream_t stream) {
    const float* x   = (const float*)d_in[0];
    const float* gw  = (const float*)d_in[1];
    const float* w1  = (const float*)d_in[2];
    const float* b1  = (const float*)d_in[3];
    const float* w2  = (const float*)d_in[4];
    const float* b2  = (const float*)d_in[5];
    const float* w3  = (const float*)d_in[6];
    const float* b3  = (const float*)d_in[7];
    const float* sw1 = (const float*)d_in[8];
    const float* sw2 = (const float*)d_in[9];
    const float* sw3 = (const float*)d_in[10];
    float* out = (float*)d_out;

    char* p = (char*)d_ws;
    int* counts  = (int*)(p + 0);
    int* cursor  = (int*)(p + 64);
    int* baserow = (int*)(p + 128);
    int* ntiles  = (int*)(p + 192);
    int* tileexp = (int*)(p + 256);          // 64 ints
    u16* XS = (u16*)(p + 4096);              // 5120 x 1024 bf16
    size_t off = 4096 + (size_t)MAXROWS * 1024 * 2;
    int*   idxA    = (int*)(p + off);   off += 16384;
    float* wA      = (float*)(p + off); off += 16384;
    int*   slot_of = (int*)(p + off);   off += 16384;
    u16*   H       = (u16*)(p + off);   off += (size_t)MAXROWS * 1024 * 2;
    float* X3f     = (float*)(p + off); off += (size_t)MAXROWS * 1024 * 4;
    float* Y2f     = (float*)(p + off); off += (size_t)MAXROWS * 1024 * 4;
    float* UVf     = X3f;  // alias: UV (33.5MB) lives in X3f+Y2f (42MB), dead before X3/Y2 written
    u16*   W13     = (u16*)(p + off);   off += (size_t)8 * 2048 * 1024 * 2;
    u16*   W2b     = (u16*)(p + off);   off += (size_t)8 * 1024 * 1024 * 2;
    u16*   S12     = (u16*)(p + off);   off += (size_t)4096 * 1024 * 2;
    u16*   S3b     = (u16*)(p + off);   off += (size_t)2048 * 1024 * 2;
    u16*   Xb      = (u16*)(p + off);   off += (size_t)2048 * 1024 * 2;
    u16*   G       = (u16*)(p + off);   off += (size_t)2048 * 2048 * 2;

    // zero counts/cursor + XS (pad rows must be 0)
    hipMemsetAsync(d_ws, 0, 4096 + (size_t)MAXROWS * 1024 * 2, stream);

    conv_all<<<32768, 256, 0, stream>>>(w1, w2, w3, sw1, sw2, sw3, x, W13, W2b, S12, S3b, Xb);
    gate_k<<<512, 256, 0, stream>>>(x, gw, idxA, wA, counts);
    scan_k<<<1, 64, 0, stream>>>(counts, baserow, tileexp, ntiles);
    scatter_k<<<16, 256, 0, stream>>>(idxA, baserow, cursor, slot_of);
    build_xs<<<4096, 256, 0, stream>>>(x, wA, slot_of, XS);

    // shared stage A: UV = Xb @ [sw1;sw2]^T   (M=2048,N=4096,K=1024)
    gemm_k<2><<<dim3(16, 32), 256, 0, stream>>>(Xb, S12, nullptr, nullptr, nullptr,
                                                UVf, nullptr, nullptr, nullptr, nullptr,
                                                1024, 1024, 4096);
    comb_g<<<4096, 256, 0, stream>>>(UVf, G);

    // routed stage A: [H | X3] = XS @ [w1;w3]^T per expert (M<=5120,N=2048,K=1024)
    gemm_k<0><<<dim3(MAXMT, 16), 256, 0, stream>>>(XS, W13, b1, b3, nullptr,
                                                   X3f, H, tileexp, ntiles, nullptr,
                                                   1024, 1024, 2048);
    // routed stage B: Y2 = (H @ w2^T + b2) * X3   (N=1024,K=1024)
    gemm_k<1><<<dim3(MAXMT, 8), 256, 0, stream>>>(H, W2b, b2, nullptr, X3f,
                                                  Y2f, nullptr, tileexp, ntiles, nullptr,
                                                  1024, 1024, 1024);
    // shared stage B + final combine: out = G @ sw3^T + Y2[slot0] + Y2[slot1]
    gemm_k<3><<<dim3(16, 8), 256, 0, stream>>>(G, S3b, nullptr, nullptr, Y2f,
                                               out, nullptr, nullptr, nullptr, slot_of,
                                               2048, 2048, 1024);
}

// Round 2
// 364.492 us; speedup vs baseline: 1.1247x; 1.1247x over previous
//
#include <hip/hip_runtime.h>

typedef unsigned short u16;
typedef __attribute__((ext_vector_type(4))) float floatx4;
typedef __attribute__((ext_vector_type(8))) short short8;

#define TTOK 2048
#define MAXROWS 5120   // 4096 slots + 8*128 padding
#define MAXMT 40

__device__ __forceinline__ u16 f2bf(float f) {
    union { float f; unsigned u; } v; v.f = f;
    unsigned r = v.u + 0x7FFF + ((v.u >> 16) & 1);
    return (u16)(r >> 16);
}
__device__ __forceinline__ float silu_f(float x) { return x / (1.f + __expf(-x)); }

__device__ __forceinline__ void gl_lds16(const void* g, void* l) {
    __builtin_amdgcn_global_load_lds(
        (__attribute__((address_space(1))) unsigned int*)g,
        (__attribute__((address_space(3))) unsigned int*)l, 16, 0, 0);
}

// ---- convert all fp32 weights (+x) to bf16 into workspace, one pass ----
__global__ void conv_all(const float* __restrict__ w1, const float* __restrict__ w2,
                         const float* __restrict__ w3, const float* __restrict__ sw1,
                         const float* __restrict__ sw2, const float* __restrict__ sw3,
                         const float* __restrict__ x,
                         u16* __restrict__ W13, u16* __restrict__ W2b,
                         u16* __restrict__ S12, u16* __restrict__ S3b,
                         u16* __restrict__ Xb) {
    long j = (long)blockIdx.x * 256 + threadIdx.x;
    const float* src; u16* dst; long d;
    if (j < 2097152) {                       // w1 -> W13 rows [0,1024) of each expert
        long e = j >> 18; src = w1; dst = W13; d = j + (e << 18);
    } else if ((j -= 2097152) < 2097152) {   // w3 -> W13 rows [1024,2048)
        long e = j >> 18; src = w3; dst = W13; d = j + (e << 18) + 262144;
    } else if ((j -= 2097152) < 2097152) { src = w2;  dst = W2b; d = j; }
    else if ((j -= 2097152) < 524288)    { src = sw1; dst = S12; d = j; }
    else if ((j -= 524288) < 524288)     { src = sw2; dst = S12; d = j + 524288; }
    else if ((j -= 524288) < 524288)     { src = sw3; dst = S3b; d = j; }
    else { j -= 524288; src = x; dst = Xb; d = j; }
    float4 v = ((const float4*)src)[j];
    ushort4 o; o.x = f2bf(v.x); o.y = f2bf(v.y); o.z = f2bf(v.z); o.w = f2bf(v.w);
    ((ushort4*)dst)[d] = o;
}

// ---- gate: logits -> softmax -> top2. NO atomics (cache-line bounce was 55us) ----
__global__ void gate_k(const float* __restrict__ x, const float* __restrict__ gw,
                       int* __restrict__ idxA, float* __restrict__ wA) {
    int w = threadIdx.x >> 6, lane = threadIdx.x & 63;
    int t = blockIdx.x * 4 + w;
    const float* xr = x + (size_t)t * 1024;
    float acc[8];
#pragma unroll
    for (int e = 0; e < 8; e++) acc[e] = 0.f;
#pragma unroll
    for (int i = 0; i < 16; i++) {
        float xv = xr[lane + (i << 6)];
#pragma unroll
        for (int e = 0; e < 8; e++) acc[e] += xv * gw[e * 1024 + lane + (i << 6)];
    }
#pragma unroll
    for (int e = 0; e < 8; e++)
        for (int off = 32; off > 0; off >>= 1) acc[e] += __shfl_xor(acc[e], off);
    if (lane == 0) {
        float m = acc[0];
#pragma unroll
        for (int e = 1; e < 8; e++) m = fmaxf(m, acc[e]);
        float p[8], s = 0.f;
#pragma unroll
        for (int e = 0; e < 8; e++) { p[e] = __expf(acc[e] - m); s += p[e]; }
        float inv = 1.f / s;
#pragma unroll
        for (int e = 0; e < 8; e++) p[e] *= inv;
        int i0 = 0;
#pragma unroll
        for (int e = 1; e < 8; e++) if (p[e] > p[i0]) i0 = e;
        int i1 = (i0 == 0) ? 1 : 0;
        for (int e = i1 + 1; e < 8; e++) if (e != i0 && p[e] > p[i1]) i1 = e;
        idxA[2 * t] = i0; idxA[2 * t + 1] = i1;
        wA[2 * t] = p[i0]; wA[2 * t + 1] = p[i1];
    }
}

// ---- single-wave deterministic rank/scatter: histogram + shuffle scan, 0 atomics ----
// lane l owns slots [64l, 64l+64). Replaces scan_k + scatter_k.
__global__ void rank_k(const int* __restrict__ idxA, int* __restrict__ tileexp,
                       int* __restrict__ ntiles, int* __restrict__ slot_of) {
    int lane = threadIdx.x;  // 64 lanes, 1 block
    const int* my = idxA + lane * 64;
    int h[8];
#pragma unroll
    for (int e = 0; e < 8; e++) h[e] = 0;
    for (int i = 0; i < 64; i++) {
        int v = my[i];
#pragma unroll
        for (int e = 0; e < 8; e++) h[e] += (v == e);
    }
    int excl[8], tot[8];
#pragma unroll
    for (int e = 0; e < 8; e++) {
        int inc = h[e];
        for (int off = 1; off < 64; off <<= 1) {
            int up = __shfl_up(inc, off);
            if (lane >= off) inc += up;
        }
        excl[e] = inc - h[e];
        tot[e] = __shfl(inc, 63);
    }
    // tile bases (all lanes compute identically)
    int base[8], tiles = 0;
#pragma unroll
    for (int e = 0; e < 8; e++) {
        base[e] = tiles * 128;
        tiles += (tot[e] + 127) >> 7;
    }
    if (lane == 0) {
        ntiles[0] = tiles;
        int t = 0;
        for (int e = 0; e < 8; e++) {
            int te = (tot[e] + 127) >> 7;
            for (int j = 0; j < te; j++) tileexp[t++] = e;
        }
    }
    int c[8];
#pragma unroll
    for (int e = 0; e < 8; e++) c[e] = base[e] + excl[e];
    for (int i = 0; i < 64; i++) {
        int v = my[i], slot = 0;
#pragma unroll
        for (int e = 0; e < 8; e++) slot += (v == e) ? c[e] : 0;
#pragma unroll
        for (int e = 0; e < 8; e++) c[e] += (v == e);
        slot_of[lane * 64 + i] = slot;
    }
}

// xs[slot] = x[t] * weight  (bf16), one block per token-slot
__global__ void build_xs(const float* __restrict__ x, const float* __restrict__ wA,
                         const int* __restrict__ slot_of, u16* __restrict__ XS) {
    int s = blockIdx.x, i = threadIdx.x;
    int t = s >> 1; float w = wA[s]; int slot = slot_of[s];
    float4 v = ((const float4*)(x + (size_t)t * 1024))[i];
    ushort4 o; o.x = f2bf(v.x * w); o.y = f2bf(v.y * w); o.z = f2bf(v.z * w); o.w = f2bf(v.w * w);
    ((ushort4*)(XS + (size_t)slot * 1024))[i] = o;
}

// G[t][c] = bf16(silu(U)*V) from UV (T x 4096 fp32)
__global__ void comb_g(const float* __restrict__ UV, u16* __restrict__ G) {
    int i = blockIdx.x * 256 + threadIdx.x;  // 2048*512
    int t = i >> 9, c4 = i & 511;
    float4 u = ((const float4*)UV)[(size_t)t * 1024 + c4];
    float4 v = ((const float4*)UV)[(size_t)t * 1024 + 512 + c4];
    ushort4 o;
    o.x = f2bf(silu_f(u.x) * v.x); o.y = f2bf(silu_f(u.y) * v.y);
    o.z = f2bf(silu_f(u.z) * v.z); o.w = f2bf(silu_f(u.w) * v.w);
    ((ushort4*)G)[(size_t)t * 512 + c4] = o;
}

// ---- m97-style bf16 TN GEMM, 128x128 tile, BK=32, fused epilogues ----
template <int MODE>
__global__ __launch_bounds__(256) void gemm_k(
    const u16* __restrict__ A, const u16* __restrict__ Bw,
    const float* __restrict__ biasA, const float* __restrict__ biasB,
    const float* __restrict__ aux, float* __restrict__ outf, u16* __restrict__ outh,
    const int* __restrict__ tileexp, const int* __restrict__ ntiles,
    const int* __restrict__ slot_of, int lda, int K, int N) {
    __shared__ u16 ldsA[128 * 32];
    __shared__ u16 ldsB[128 * 32];

    int mt = blockIdx.x;
    int e = 0;
    if (MODE == 0 || MODE == 1) {
        if (mt >= ntiles[0]) return;
        e = tileexp[mt];
    }
    const u16* Bp = Bw + (size_t)e * N * K;
    int m0 = mt * 128, n0 = blockIdx.y * 128;
    int tid = threadIdx.x, w = tid >> 6, lane = tid & 63;
    int wm = w >> 1, wn = w & 1;

    floatx4 acc[4][4];
#pragma unroll
    for (int i = 0; i < 4; i++)
#pragma unroll
        for (int j = 0; j < 4; j++) { floatx4 z = {0.f, 0.f, 0.f, 0.f}; acc[i][j] = z; }

    int rloc = lane >> 2, clds = lane & 3, q = lane >> 4, l15 = lane & 15;

    for (int k0 = 0; k0 < K; k0 += 32) {
#pragma unroll
        for (int t = 0; t < 2; t++) {
            int r = (w << 4) + (t << 6) + rloc;  // tile row 0..127
            int cg = clds ^ ((r >> 1) & 3);      // xor-swizzled granule
            gl_lds16(A + (size_t)(m0 + r) * lda + k0 + (cg << 3),
                     &ldsA[((w << 4) + (t << 6)) * 32]);
            gl_lds16(Bp + (size_t)(n0 + r) * K + k0 + (cg << 3),
                     &ldsB[((w << 4) + (t << 6)) * 32]);
        }
        __syncthreads();

        short8 af[4], bf[4];
#pragma unroll
        for (int i = 0; i < 4; i++) {
            int rr = (wm << 6) + (i << 4) + l15;
            int c = q ^ ((rr >> 1) & 3);
            af[i] = *(const short8*)&ldsA[rr * 32 + (c << 3)];
        }
#pragma unroll
        for (int j = 0; j < 4; j++) {
            int rr = (wn << 6) + (j << 4) + l15;
            int c = q ^ ((rr >> 1) & 3);
            bf[j] = *(const short8*)&ldsB[rr * 32 + (c << 3)];
        }
#pragma unroll
        for (int i = 0; i < 4; i++)
#pragma unroll
            for (int j = 0; j < 4; j++)
                acc[i][j] = __builtin_amdgcn_mfma_f32_16x16x32_bf16(af[i], bf[j], acc[i][j], 0, 0, 0);
        __syncthreads();
    }

    // epilogue: element (row,col): col=lane&15, row=(lane>>4)*4+reg
#pragma unroll
    for (int i = 0; i < 4; i++) {
        int rowb = m0 + (wm << 6) + (i << 4) + (q << 2);
#pragma unroll
        for (int j = 0; j < 4; j++) {
            int col = n0 + (wn << 6) + (j << 4) + l15;
#pragma unroll
            for (int r = 0; r < 4; r++) {
                float v = acc[i][j][r];
                int rw = rowb + r;
                if (MODE == 0) {
                    if (col < 1024) {
                        float h = silu_f(v + biasA[e * 1024 + col]);
                        outh[(size_t)rw * 1024 + col] = f2bf(h);
                    } else {
                        int c2 = col - 1024;
                        outf[(size_t)rw * 1024 + c2] = v + biasB[e * 1024 + c2];
                    }
                } else if (MODE == 1) {
                    float y = (v + biasA[e * 1024 + col]) * aux[(size_t)rw * 1024 + col];
                    outf[(size_t)rw * 1024 + col] = y;
                } else if (MODE == 2) {
                    outf[(size_t)rw * 4096 + col] = v;
                } else {
                    float y = aux[(size_t)slot_of[rw * 2] * 1024 + col] +
                              aux[(size_t)slot_of[rw * 2 + 1] * 1024 + col];
                    outf[(size_t)rw * 1024 + col] = v + y;
                }
            }
        }
    }
}

extern "C" void kernel_launch(void* const* d_in, const int* in_sizes, int n_in,
                              void* d_out, int out_size, void* d_ws, size_t ws_size,
                              hipStream_t stream) {
    const float* x   = (const float*)d_in[0];
    const float* gw  = (const float*)d_in[1];
    const float* w1  = (const float*)d_in[2];
    const float* b1  = (const float*)d_in[3];
    const float* w2  = (const float*)d_in[4];
    const float* b2  = (const float*)d_in[5];
    const float* w3  = (const float*)d_in[6];
    const float* b3  = (const float*)d_in[7];
    const float* sw1 = (const float*)d_in[8];
    const float* sw2 = (const float*)d_in[9];
    const float* sw3 = (const float*)d_in[10];
    float* out = (float*)d_out;

    char* p = (char*)d_ws;
    int* ntiles  = (int*)(p + 192);
    int* tileexp = (int*)(p + 256);          // 64 ints
    u16* XS = (u16*)(p + 4096);              // 5120 x 1024 bf16
    size_t off = 4096 + (size_t)MAXROWS * 1024 * 2;
    int*   idxA    = (int*)(p + off);   off += 16384;
    float* wA      = (float*)(p + off); off += 16384;
    int*   slot_of = (int*)(p + off);   off += 16384;
    u16*   H       = (u16*)(p + off);   off += (size_t)MAXROWS * 1024 * 2;
    float* X3f     = (float*)(p + off); off += (size_t)MAXROWS * 1024 * 4;
    float* Y2f     = (float*)(p + off); off += (size_t)MAXROWS * 1024 * 4;
    float* UVf     = X3f;  // alias: UV dead before X3/Y2 written
    u16*   W13     = (u16*)(p + off);   off += (size_t)8 * 2048 * 1024 * 2;
    u16*   W2b     = (u16*)(p + off);   off += (size_t)8 * 1024 * 1024 * 2;
    u16*   S12     = (u16*)(p + off);   off += (size_t)4096 * 1024 * 2;
    u16*   S3b     = (u16*)(p + off);   off += (size_t)2048 * 1024 * 2;
    u16*   Xb      = (u16*)(p + off);   off += (size_t)2048 * 1024 * 2;
    u16*   G       = (u16*)(p + off);   off += (size_t)2048 * 2048 * 2;

    conv_all<<<32768, 256, 0, stream>>>(w1, w2, w3, sw1, sw2, sw3, x, W13, W2b, S12, S3b, Xb);
    gate_k<<<512, 256, 0, stream>>>(x, gw, idxA, wA);
    rank_k<<<1, 64, 0, stream>>>(idxA, tileexp, ntiles, slot_of);
    build_xs<<<4096, 256, 0, stream>>>(x, wA, slot_of, XS);

    // shared stage A: UV = Xb @ [sw1;sw2]^T   (M=2048,N=4096,K=1024)
    gemm_k<2><<<dim3(16, 32), 256, 0, stream>>>(Xb, S12, nullptr, nullptr, nullptr,
                                                UVf, nullptr, nullptr, nullptr, nullptr,
                                                1024, 1024, 4096);
    comb_g<<<4096, 256, 0, stream>>>(UVf, G);

    // routed stage A: [H | X3] = XS @ [w1;w3]^T per expert
    gemm_k<0><<<dim3(MAXMT, 16), 256, 0, stream>>>(XS, W13, b1, b3, nullptr,
                                                   X3f, H, tileexp, ntiles, nullptr,
                                                   1024, 1024, 2048);
    // routed stage B: Y2 = (H @ w2^T + b2) * X3
    gemm_k<1><<<dim3(MAXMT, 8), 256, 0, stream>>>(H, W2b, b2, nullptr, X3f,
                                                  Y2f, nullptr, tileexp, ntiles, nullptr,
                                                  1024, 1024, 1024);
    // shared stage B + final combine: out = G @ sw3^T + Y2[slot0] + Y2[slot1]
    gemm_k<3><<<dim3(16, 8), 256, 0, stream>>>(G, S3b, nullptr, nullptr, Y2f,
                                               out, nullptr, nullptr, nullptr, slot_of,
                                               2048, 2048, 1024);
}

// Round 3
// 334.048 us; speedup vs baseline: 1.2272x; 1.0911x over previous
//
#include <hip/hip_runtime.h>

typedef unsigned short u16;
typedef __attribute__((ext_vector_type(4))) float floatx4;
typedef __attribute__((ext_vector_type(8))) short short8;

#define MAXROWS 5120   // 4096 slots + 8*128 padding
#define MAXMT 40

__device__ __forceinline__ u16 f2bf(float f) {
    union { float f; unsigned u; } v; v.f = f;
    unsigned r = v.u + 0x7FFF + ((v.u >> 16) & 1);
    return (u16)(r >> 16);
}
__device__ __forceinline__ float bf2f(u16 h) {
    union { unsigned u; float f; } v; v.u = ((unsigned)h) << 16; return v.f;
}
__device__ __forceinline__ float silu_f(float x) { return x / (1.f + __expf(-x)); }

__device__ __forceinline__ void gl_lds16(const void* g, void* l) {
    __builtin_amdgcn_global_load_lds(
        (__attribute__((address_space(1))) unsigned int*)g,
        (__attribute__((address_space(3))) unsigned int*)l, 16, 0, 0);
}

// ---- fused: gate (blocks 0..511) + fp32->bf16 conversion (blocks 512..33279) ----
// S12 layout: 32-row groups: rows g*32+0..15 = sw1[g*16..], g*32+16..31 = sw2[g*16..]
// so a 16-wide B-frag pair (j even, j odd) holds (u, v) of the SAME logical col per lane.
__global__ void conv_gate(const float* __restrict__ w1, const float* __restrict__ w2,
                          const float* __restrict__ w3, const float* __restrict__ sw1,
                          const float* __restrict__ sw2, const float* __restrict__ sw3,
                          const float* __restrict__ x, const float* __restrict__ gw,
                          u16* __restrict__ W13, u16* __restrict__ W2b,
                          u16* __restrict__ S12, u16* __restrict__ S3b,
                          u16* __restrict__ Xb,
                          int* __restrict__ idxA, float* __restrict__ wA) {
    int bid = blockIdx.x;
    if (bid < 512) {  // ---- gate ----
        int w = threadIdx.x >> 6, lane = threadIdx.x & 63;
        int t = bid * 4 + w;
        const float* xr = x + (size_t)t * 1024;
        float acc[8];
#pragma unroll
        for (int e = 0; e < 8; e++) acc[e] = 0.f;
#pragma unroll
        for (int i = 0; i < 16; i++) {
            float xv = xr[lane + (i << 6)];
#pragma unroll
            for (int e = 0; e < 8; e++) acc[e] += xv * gw[e * 1024 + lane + (i << 6)];
        }
#pragma unroll
        for (int e = 0; e < 8; e++)
            for (int off = 32; off > 0; off >>= 1) acc[e] += __shfl_xor(acc[e], off);
        if (lane == 0) {
            float m = acc[0];
#pragma unroll
            for (int e = 1; e < 8; e++) m = fmaxf(m, acc[e]);
            float p[8], s = 0.f;
#pragma unroll
            for (int e = 0; e < 8; e++) { p[e] = __expf(acc[e] - m); s += p[e]; }
            float inv = 1.f / s;
#pragma unroll
            for (int e = 0; e < 8; e++) p[e] *= inv;
            int i0 = 0;
#pragma unroll
            for (int e = 1; e < 8; e++) if (p[e] > p[i0]) i0 = e;
            int i1 = (i0 == 0) ? 1 : 0;
            for (int e = i1 + 1; e < 8; e++) if (e != i0 && p[e] > p[i1]) i1 = e;
            idxA[2 * t] = i0; idxA[2 * t + 1] = i1;
            wA[2 * t] = p[i0]; wA[2 * t + 1] = p[i1];
        }
        return;
    }
    // ---- conversion ----
    long j = (long)(bid - 512) * 256 + threadIdx.x;
    const float* src; u16* dst; long d;
    if (j < 2097152) {                       // w1 -> W13 rows [0,1024) per expert
        long e = j >> 18; src = w1; dst = W13; d = j + (e << 18);
    } else if ((j -= 2097152) < 2097152) {   // w3 -> W13 rows [1024,2048)
        long e = j >> 18; src = w3; dst = W13; d = j + (e << 18) + 262144;
    } else if ((j -= 2097152) < 2097152) { src = w2;  dst = W2b; d = j; }
    else if ((j -= 2097152) < 524288) {      // sw1 -> S12 interleaved
        long rr = j >> 8, c4 = j & 255;
        long br = ((rr >> 4) << 5) + (rr & 15);
        src = sw1; dst = S12; d = (br << 8) + c4;
    } else if ((j -= 524288) < 524288) {     // sw2 -> S12 interleaved (+16)
        long rr = j >> 8, c4 = j & 255;
        long br = ((rr >> 4) << 5) + 16 + (rr & 15);
        src = sw2; dst = S12; d = (br << 8) + c4;
    } else if ((j -= 524288) < 524288)     { src = sw3; dst = S3b; d = j; }
    else { j -= 524288; src = x; dst = Xb; d = j; }
    float4 v = ((const float4*)src)[j];
    ushort4 o; o.x = f2bf(v.x); o.y = f2bf(v.y); o.z = f2bf(v.z); o.w = f2bf(v.w);
    ((ushort4*)dst)[d] = o;
}

// ---- single-wave deterministic rank/scatter (0 atomics) ----
__global__ void rank_k(const int* __restrict__ idxA, int* __restrict__ tileexp,
                       int* __restrict__ ntiles, int* __restrict__ slot_of) {
    int lane = threadIdx.x;
    const int* my = idxA + lane * 64;
    int h[8];
#pragma unroll
    for (int e = 0; e < 8; e++) h[e] = 0;
    for (int i = 0; i < 64; i++) {
        int v = my[i];
#pragma unroll
        for (int e = 0; e < 8; e++) h[e] += (v == e);
    }
    int excl[8], tot[8];
#pragma unroll
    for (int e = 0; e < 8; e++) {
        int inc = h[e];
        for (int off = 1; off < 64; off <<= 1) {
            int up = __shfl_up(inc, off);
            if (lane >= off) inc += up;
        }
        excl[e] = inc - h[e];
        tot[e] = __shfl(inc, 63);
    }
    int base[8], tiles = 0;
#pragma unroll
    for (int e = 0; e < 8; e++) {
        base[e] = tiles * 128;
        tiles += (tot[e] + 127) >> 7;
    }
    if (lane == 0) {
        ntiles[0] = tiles;
        int t = 0;
        for (int e = 0; e < 8; e++) {
            int te = (tot[e] + 127) >> 7;
            for (int j = 0; j < te; j++) tileexp[t++] = e;
        }
    }
    int c[8];
#pragma unroll
    for (int e = 0; e < 8; e++) c[e] = base[e] + excl[e];
    for (int i = 0; i < 64; i++) {
        int v = my[i], slot = 0;
#pragma unroll
        for (int e = 0; e < 8; e++) slot += (v == e) ? c[e] : 0;
#pragma unroll
        for (int e = 0; e < 8; e++) c[e] += (v == e);
        slot_of[lane * 64 + i] = slot;
    }
}

// xs[slot] = x[t] * weight (bf16)
__global__ void build_xs(const float* __restrict__ x, const float* __restrict__ wA,
                         const int* __restrict__ slot_of, u16* __restrict__ XS) {
    int s = blockIdx.x, i = threadIdx.x;
    int t = s >> 1; float w = wA[s]; int slot = slot_of[s];
    float4 v = ((const float4*)(x + (size_t)t * 1024))[i];
    ushort4 o; o.x = f2bf(v.x * w); o.y = f2bf(v.y * w); o.z = f2bf(v.z * w); o.w = f2bf(v.w * w);
    ((ushort4*)(XS + (size_t)slot * 1024))[i] = o;
}

// ---- merged stage-A GEMM: seg<640 routed [H|X3h], else shared (G fused silu(u)*v) ----
__global__ __launch_bounds__(256) void gemm_A(
    const u16* __restrict__ XS, const u16* __restrict__ Xb,
    const u16* __restrict__ W13, const u16* __restrict__ S12,
    const float* __restrict__ b1, const float* __restrict__ b3,
    u16* __restrict__ H, u16* __restrict__ X3h, u16* __restrict__ G,
    const int* __restrict__ tileexp, const int* __restrict__ ntiles) {
    __shared__ u16 ldsA[128 * 32];
    __shared__ u16 ldsB[128 * 32];
    int seg = blockIdx.x;
    const u16 *Ab, *Bb; int mt, nt, e = 0; bool routed;
    if (seg < 640) {
        routed = true; mt = seg % 40; nt = seg / 40;
        if (mt >= ntiles[0]) return;
        e = tileexp[mt];
        Ab = XS; Bb = W13 + ((size_t)e << 21);
    } else {
        routed = false; int s = seg - 640; mt = s & 15; nt = s >> 4;
        Ab = Xb; Bb = S12;
    }
    int m0 = mt * 128, n0 = nt * 128;
    int tid = threadIdx.x, w = tid >> 6, lane = tid & 63;
    int wm = w >> 1, wn = w & 1;

    floatx4 acc[4][4];
#pragma unroll
    for (int i = 0; i < 4; i++)
#pragma unroll
        for (int j = 0; j < 4; j++) { floatx4 z = {0.f, 0.f, 0.f, 0.f}; acc[i][j] = z; }

    int rloc = lane >> 2, clds = lane & 3, q = lane >> 4, l15 = lane & 15;

    for (int k0 = 0; k0 < 1024; k0 += 32) {
#pragma unroll
        for (int t = 0; t < 2; t++) {
            int r = (w << 4) + (t << 6) + rloc;
            int cg = clds ^ ((r >> 1) & 3);
            gl_lds16(Ab + (size_t)(m0 + r) * 1024 + k0 + (cg << 3),
                     &ldsA[((w << 4) + (t << 6)) * 32]);
            gl_lds16(Bb + (size_t)(n0 + r) * 1024 + k0 + (cg << 3),
                     &ldsB[((w << 4) + (t << 6)) * 32]);
        }
        __syncthreads();
        short8 af[4], bf[4];
#pragma unroll
        for (int i = 0; i < 4; i++) {
            int rr = (wm << 6) + (i << 4) + l15;
            int c = q ^ ((rr >> 1) & 3);
            af[i] = *(const short8*)&ldsA[rr * 32 + (c << 3)];
        }
#pragma unroll
        for (int j = 0; j < 4; j++) {
            int rr = (wn << 6) + (j << 4) + l15;
            int c = q ^ ((rr >> 1) & 3);
            bf[j] = *(const short8*)&ldsB[rr * 32 + (c << 3)];
        }
#pragma unroll
        for (int i = 0; i < 4; i++)
#pragma unroll
            for (int j = 0; j < 4; j++)
                acc[i][j] = __builtin_amdgcn_mfma_f32_16x16x32_bf16(af[i], bf[j], acc[i][j], 0, 0, 0);
        __syncthreads();
    }

    if (routed) {
#pragma unroll
        for (int i = 0; i < 4; i++) {
            int rowb = m0 + (wm << 6) + (i << 4) + (q << 2);
#pragma unroll
            for (int j = 0; j < 4; j++) {
                int col = n0 + (wn << 6) + (j << 4) + l15;
#pragma unroll
                for (int r = 0; r < 4; r++) {
                    float v = acc[i][j][r];
                    int rw = rowb + r;
                    if (nt < 8) {
                        H[(size_t)rw * 1024 + col] = f2bf(silu_f(v + b1[e * 1024 + col]));
                    } else {
                        int c2 = col - 1024;
                        X3h[(size_t)rw * 1024 + c2] = f2bf(v + b3[e * 1024 + c2]);
                    }
                }
            }
        }
    } else {
        // frag pair (j, j+1) = (u, v) of the same logical col: lcol = (br_base>>5)<<4 | l15
#pragma unroll
        for (int i = 0; i < 4; i++) {
            int rowb = m0 + (wm << 6) + (i << 4) + (q << 2);
#pragma unroll
            for (int jp = 0; jp < 4; jp += 2) {
                int brb = n0 + (wn << 6) + (jp << 4);
                int lcol = ((brb >> 5) << 4) + l15;
#pragma unroll
                for (int r = 0; r < 4; r++) {
                    float u = acc[i][jp][r], v = acc[i][jp + 1][r];
                    G[(size_t)(rowb + r) * 2048 + lcol] = f2bf(silu_f(u) * v);
                }
            }
        }
    }
}

// ---- merged stage-B GEMM, split-K=2: seg<640 routed P_k=(acc+b2[k0])*x3, else shared Z_k ----
__global__ __launch_bounds__(256) void gemm_B(
    const u16* __restrict__ H, const u16* __restrict__ G,
    const u16* __restrict__ W2b, const u16* __restrict__ S3b,
    const float* __restrict__ b2, const u16* __restrict__ X3h,
    u16* __restrict__ P0, u16* __restrict__ P1,
    float* __restrict__ Z0, float* __restrict__ Z1,
    const int* __restrict__ tileexp, const int* __restrict__ ntiles) {
    __shared__ u16 ldsA[128 * 32];
    __shared__ u16 ldsB[128 * 32];
    int seg = blockIdx.x;
    const u16 *Ab, *Bb; int mt, nt, kc, lda, kbeg, e = 0; bool routed;
    if (seg < 640) {
        routed = true; kc = seg & 1; int s2 = seg >> 1;
        mt = s2 % 40; nt = s2 / 40;
        if (mt >= ntiles[0]) return;
        e = tileexp[mt];
        Ab = H; Bb = W2b + ((size_t)e << 20); lda = 1024; kbeg = kc << 9;   // 512-chunk
    } else {
        routed = false; int s = seg - 640; kc = s & 1; int s2 = s >> 1;
        mt = s2 & 15; nt = s2 >> 4;
        Ab = G; Bb = S3b; lda = 2048; kbeg = kc << 10;                     // 1024-chunk
    }
    int kend = kbeg + (routed ? 512 : 1024);
    int m0 = mt * 128, n0 = nt * 128;
    int tid = threadIdx.x, w = tid >> 6, lane = tid & 63;
    int wm = w >> 1, wn = w & 1;

    floatx4 acc[4][4];
#pragma unroll
    for (int i = 0; i < 4; i++)
#pragma unroll
        for (int j = 0; j < 4; j++) { floatx4 z = {0.f, 0.f, 0.f, 0.f}; acc[i][j] = z; }

    int rloc = lane >> 2, clds = lane & 3, q = lane >> 4, l15 = lane & 15;

    for (int k0 = kbeg; k0 < kend; k0 += 32) {
#pragma unroll
        for (int t = 0; t < 2; t++) {
            int r = (w << 4) + (t << 6) + rloc;
            int cg = clds ^ ((r >> 1) & 3);
            gl_lds16(Ab + (size_t)(m0 + r) * lda + k0 + (cg << 3),
                     &ldsA[((w << 4) + (t << 6)) * 32]);
            gl_lds16(Bb + (size_t)(n0 + r) * lda + k0 + (cg << 3),
                     &ldsB[((w << 4) + (t << 6)) * 32]);
        }
        __syncthreads();
        short8 af[4], bf[4];
#pragma unroll
        for (int i = 0; i < 4; i++) {
            int rr = (wm << 6) + (i << 4) + l15;
            int c = q ^ ((rr >> 1) & 3);
            af[i] = *(const short8*)&ldsA[rr * 32 + (c << 3)];
        }
#pragma unroll
        for (int j = 0; j < 4; j++) {
            int rr = (wn << 6) + (j << 4) + l15;
            int c = q ^ ((rr >> 1) & 3);
            bf[j] = *(const short8*)&ldsB[rr * 32 + (c << 3)];
        }
#pragma unroll
        for (int i = 0; i < 4; i++)
#pragma unroll
            for (int j = 0; j < 4; j++)
                acc[i][j] = __builtin_amdgcn_mfma_f32_16x16x32_bf16(af[i], bf[j], acc[i][j], 0, 0, 0);
        __syncthreads();
    }

    if (routed) {
        u16* Pk = kc ? P1 : P0;
#pragma unroll
        for (int i = 0; i < 4; i++) {
            int rowb = m0 + (wm << 6) + (i << 4) + (q << 2);
#pragma unroll
            for (int j = 0; j < 4; j++) {
                int col = n0 + (wn << 6) + (j << 4) + l15;
#pragma unroll
                for (int r = 0; r < 4; r++) {
                    int rw = rowb + r;
                    float v = acc[i][j][r] + (kc == 0 ? b2[e * 1024 + col] : 0.f);
                    float pv = v * bf2f(X3h[(size_t)rw * 1024 + col]);
                    Pk[(size_t)rw * 1024 + col] = f2bf(pv);
                }
            }
        }
    } else {
        float* Zk = kc ? Z1 : Z0;
#pragma unroll
        for (int i = 0; i < 4; i++) {
            int rowb = m0 + (wm << 6) + (i << 4) + (q << 2);
#pragma unroll
            for (int j = 0; j < 4; j++) {
                int col = n0 + (wn << 6) + (j << 4) + l15;
#pragma unroll
                for (int r = 0; r < 4; r++)
                    Zk[(size_t)(rowb + r) * 1024 + col] = acc[i][j][r];
            }
        }
    }
}

// out[t] = Z0+Z1 + P0[s0]+P1[s0] + P0[s1]+P1[s1]
__global__ void final_k(const float* __restrict__ Z0, const float* __restrict__ Z1,
                        const u16* __restrict__ P0, const u16* __restrict__ P1,
                        const int* __restrict__ slot_of, float* __restrict__ out) {
    int i = blockIdx.x * 256 + threadIdx.x;   // 524288 float4 units
    int t = i >> 8, c4 = i & 255;
    int s0 = slot_of[2 * t], s1 = slot_of[2 * t + 1];
    float4 z0 = ((const float4*)Z0)[(size_t)t * 256 + c4];
    float4 z1 = ((const float4*)Z1)[(size_t)t * 256 + c4];
    ushort4 a0 = ((const ushort4*)P0)[(size_t)s0 * 256 + c4];
    ushort4 a1 = ((const ushort4*)P1)[(size_t)s0 * 256 + c4];
    ushort4 c0 = ((const ushort4*)P0)[(size_t)s1 * 256 + c4];
    ushort4 c1 = ((const ushort4*)P1)[(size_t)s1 * 256 + c4];
    float4 o;
    o.x = z0.x + z1.x + bf2f(a0.x) + bf2f(a1.x) + bf2f(c0.x) + bf2f(c1.x);
    o.y = z0.y + z1.y + bf2f(a0.y) + bf2f(a1.y) + bf2f(c0.y) + bf2f(c1.y);
    o.z = z0.z + z1.z + bf2f(a0.z) + bf2f(a1.z) + bf2f(c0.z) + bf2f(c1.z);
    o.w = z0.w + z1.w + bf2f(a0.w) + bf2f(a1.w) + bf2f(c0.w) + bf2f(c1.w);
    ((float4*)out)[(size_t)t * 256 + c4] = o;
}

extern "C" void kernel_launch(void* const* d_in, const int* in_sizes, int n_in,
                              void* d_out, int out_size, void* d_ws, size_t ws_size,
                              hipStream_t stream) {
    const float* x   = (const float*)d_in[0];
    const float* gw  = (const float*)d_in[1];
    const float* w1  = (const float*)d_in[2];
    const float* b1  = (const float*)d_in[3];
    const float* w2  = (const float*)d_in[4];
    const float* b2  = (const float*)d_in[5];
    const float* w3  = (const float*)d_in[6];
    const float* b3  = (const float*)d_in[7];
    const float* sw1 = (const float*)d_in[8];
    const float* sw2 = (const float*)d_in[9];
    const float* sw3 = (const float*)d_in[10];
    float* out = (float*)d_out;

    char* p = (char*)d_ws;
    int* ntiles  = (int*)(p + 192);
    int* tileexp = (int*)(p + 256);
    size_t off = 4096;
    u16*   XS      = (u16*)(p + off);   off += (size_t)MAXROWS * 1024 * 2;
    int*   idxA    = (int*)(p + off);   off += 16384;
    float* wA      = (float*)(p + off); off += 16384;
    int*   slot_of = (int*)(p + off);   off += 16384;
    u16*   H       = (u16*)(p + off);   off += (size_t)MAXROWS * 1024 * 2;
    u16*   X3h     = (u16*)(p + off);   off += (size_t)MAXROWS * 1024 * 2;
    u16*   P0      = (u16*)(p + off);   off += (size_t)MAXROWS * 1024 * 2;
    u16*   P1      = (u16*)(p + off);   off += (size_t)MAXROWS * 1024 * 2;
    float* Z0      = (float*)(p + off); off += (size_t)2048 * 1024 * 4;
    float* Z1      = (float*)(p + off); off += (size_t)2048 * 1024 * 4;
    u16*   W13     = (u16*)(p + off);   off += (size_t)8 * 2048 * 1024 * 2;
    u16*   W2b     = (u16*)(p + off);   off += (size_t)8 * 1024 * 1024 * 2;
    u16*   S12     = (u16*)(p + off);   off += (size_t)4096 * 1024 * 2;
    u16*   S3b     = (u16*)(p + off);   off += (size_t)1024 * 2048 * 2;
    u16*   Xb      = (u16*)(p + off);   off += (size_t)2048 * 1024 * 2;
    u16*   G       = (u16*)(p + off);   off += (size_t)2048 * 2048 * 2;

    conv_gate<<<33280, 256, 0, stream>>>(w1, w2, w3, sw1, sw2, sw3, x, gw,
                                         W13, W2b, S12, S3b, Xb, idxA, wA);
    rank_k<<<1, 64, 0, stream>>>(idxA, tileexp, ntiles, slot_of);
    build_xs<<<4096, 256, 0, stream>>>(x, wA, slot_of, XS);

    gemm_A<<<1152, 256, 0, stream>>>(XS, Xb, W13, S12, b1, b3, H, X3h, G,
                                     tileexp, ntiles);
    gemm_B<<<896, 256, 0, stream>>>(H, G, W2b, S3b, b2, X3h, P0, P1, Z0, Z1,
                                    tileexp, ntiles);
    final_k<<<2048, 256, 0, stream>>>(Z0, Z1, P0, P1, slot_of, out);
}

// Round 4
// 322.419 us; speedup vs baseline: 1.2715x; 1.0361x over previous
//
#include <hip/hip_runtime.h>

typedef unsigned short u16;
typedef __attribute__((ext_vector_type(4))) float floatx4;
typedef __attribute__((ext_vector_type(8))) short short8;

#define MAXROWS 5120   // 4096 slots + 8*128 padding
#define MAXMT 40

__device__ __forceinline__ u16 f2bf(float f) {
    union { float f; unsigned u; } v; v.f = f;
    unsigned r = v.u + 0x7FFF + ((v.u >> 16) & 1);
    return (u16)(r >> 16);
}
__device__ __forceinline__ float bf2f(u16 h) {
    union { unsigned u; float f; } v; v.u = ((unsigned)h) << 16; return v.f;
}
__device__ __forceinline__ float silu_f(float x) { return x / (1.f + __expf(-x)); }

__device__ __forceinline__ void gl_lds16(const void* g, void* l) {
    __builtin_amdgcn_global_load_lds(
        (__attribute__((address_space(1))) unsigned int*)g,
        (__attribute__((address_space(3))) unsigned int*)l, 16, 0, 0);
}

// ---- fused: gate (blocks 0..511) + fp32->bf16 conversion ----
// S12 layout: 32-row groups: rows g*32+0..15 = sw1[g*16..], g*32+16..31 = sw2[g*16..]
__global__ void conv_gate(const float* __restrict__ w1, const float* __restrict__ w2,
                          const float* __restrict__ w3, const float* __restrict__ sw1,
                          const float* __restrict__ sw2, const float* __restrict__ sw3,
                          const float* __restrict__ x, const float* __restrict__ gw,
                          u16* __restrict__ W13, u16* __restrict__ W2b,
                          u16* __restrict__ S12, u16* __restrict__ S3b,
                          u16* __restrict__ Xb,
                          int* __restrict__ idxA, float* __restrict__ wA) {
    int bid = blockIdx.x;
    if (bid < 512) {  // ---- gate ----
        int w = threadIdx.x >> 6, lane = threadIdx.x & 63;
        int t = bid * 4 + w;
        const float* xr = x + (size_t)t * 1024;
        float acc[8];
#pragma unroll
        for (int e = 0; e < 8; e++) acc[e] = 0.f;
#pragma unroll
        for (int i = 0; i < 16; i++) {
            float xv = xr[lane + (i << 6)];
#pragma unroll
            for (int e = 0; e < 8; e++) acc[e] += xv * gw[e * 1024 + lane + (i << 6)];
        }
#pragma unroll
        for (int e = 0; e < 8; e++)
            for (int off = 32; off > 0; off >>= 1) acc[e] += __shfl_xor(acc[e], off);
        if (lane == 0) {
            float m = acc[0];
#pragma unroll
            for (int e = 1; e < 8; e++) m = fmaxf(m, acc[e]);
            float p[8], s = 0.f;
#pragma unroll
            for (int e = 0; e < 8; e++) { p[e] = __expf(acc[e] - m); s += p[e]; }
            float inv = 1.f / s;
#pragma unroll
            for (int e = 0; e < 8; e++) p[e] *= inv;
            int i0 = 0;
#pragma unroll
            for (int e = 1; e < 8; e++) if (p[e] > p[i0]) i0 = e;
            int i1 = (i0 == 0) ? 1 : 0;
            for (int e = i1 + 1; e < 8; e++) if (e != i0 && p[e] > p[i1]) i1 = e;
            idxA[2 * t] = i0; idxA[2 * t + 1] = i1;
            wA[2 * t] = p[i0]; wA[2 * t + 1] = p[i1];
        }
        return;
    }
    long j = (long)(bid - 512) * 256 + threadIdx.x;
    const float* src; u16* dst; long d;
    if (j < 2097152) {
        long e = j >> 18; src = w1; dst = W13; d = j + (e << 18);
    } else if ((j -= 2097152) < 2097152) {
        long e = j >> 18; src = w3; dst = W13; d = j + (e << 18) + 262144;
    } else if ((j -= 2097152) < 2097152) { src = w2;  dst = W2b; d = j; }
    else if ((j -= 2097152) < 524288) {
        long rr = j >> 8, c4 = j & 255;
        long br = ((rr >> 4) << 5) + (rr & 15);
        src = sw1; dst = S12; d = (br << 8) + c4;
    } else if ((j -= 524288) < 524288) {
        long rr = j >> 8, c4 = j & 255;
        long br = ((rr >> 4) << 5) + 16 + (rr & 15);
        src = sw2; dst = S12; d = (br << 8) + c4;
    } else if ((j -= 524288) < 524288)     { src = sw3; dst = S3b; d = j; }
    else { j -= 524288; src = x; dst = Xb; d = j; }
    float4 v = ((const float4*)src)[j];
    ushort4 o; o.x = f2bf(v.x); o.y = f2bf(v.y); o.z = f2bf(v.z); o.w = f2bf(v.w);
    ((ushort4*)dst)[d] = o;
}

// ---- single-wave deterministic rank/scatter (0 atomics) ----
__global__ void rank_k(const int* __restrict__ idxA, int* __restrict__ tileexp,
                       int* __restrict__ ntiles, int* __restrict__ slot_of) {
    int lane = threadIdx.x;
    const int* my = idxA + lane * 64;
    int h[8];
#pragma unroll
    for (int e = 0; e < 8; e++) h[e] = 0;
    for (int i = 0; i < 64; i++) {
        int v = my[i];
#pragma unroll
        for (int e = 0; e < 8; e++) h[e] += (v == e);
    }
    int excl[8], tot[8];
#pragma unroll
    for (int e = 0; e < 8; e++) {
        int inc = h[e];
        for (int off = 1; off < 64; off <<= 1) {
            int up = __shfl_up(inc, off);
            if (lane >= off) inc += up;
        }
        excl[e] = inc - h[e];
        tot[e] = __shfl(inc, 63);
    }
    int base[8], tiles = 0;
#pragma unroll
    for (int e = 0; e < 8; e++) {
        base[e] = tiles * 128;
        tiles += (tot[e] + 127) >> 7;
    }
    if (lane == 0) {
        ntiles[0] = tiles;
        int t = 0;
        for (int e = 0; e < 8; e++) {
            int te = (tot[e] + 127) >> 7;
            for (int j = 0; j < te; j++) tileexp[t++] = e;
        }
    }
    int c[8];
#pragma unroll
    for (int e = 0; e < 8; e++) c[e] = base[e] + excl[e];
    for (int i = 0; i < 64; i++) {
        int v = my[i], slot = 0;
#pragma unroll
        for (int e = 0; e < 8; e++) slot += (v == e) ? c[e] : 0;
#pragma unroll
        for (int e = 0; e < 8; e++) c[e] += (v == e);
        slot_of[lane * 64 + i] = slot;
    }
}

__global__ void build_xs(const float* __restrict__ x, const float* __restrict__ wA,
                         const int* __restrict__ slot_of, u16* __restrict__ XS) {
    int s = blockIdx.x, i = threadIdx.x;
    int t = s >> 1; float w = wA[s]; int slot = slot_of[s];
    float4 v = ((const float4*)(x + (size_t)t * 1024))[i];
    ushort4 o; o.x = f2bf(v.x * w); o.y = f2bf(v.y * w); o.z = f2bf(v.z * w); o.w = f2bf(v.w * w);
    ((ushort4*)(XS + (size_t)slot * 1024))[i] = o;
}

// ======== BK=64 GEMM core ========
// LDS layout: 16 chunks of 512 u16: chunk(b,h) = band b (16 rows), k-half h (32 cols)
// addr(r, kc) = ((r>>4)*2 + (kc>>5))*512 + (r&15)*32 + granule*8 ; granule swizzled by row.
#define STAGE64(Ab, Bb, lda)                                                        \
    {                                                                               \
        _Pragma("unroll")                                                           \
        for (int t = 0; t < 2; t++) {                                               \
            int b = w + (t << 2);                                                   \
            int r = (b << 4) + rloc;                                                \
            int cg = clds ^ ((r >> 1) & 3);                                         \
            _Pragma("unroll")                                                       \
            for (int hh = 0; hh < 2; hh++) {                                        \
                gl_lds16(Ab + (size_t)(m0 + r) * lda + k0 + (hh << 5) + (cg << 3),  \
                         &ldsA[(b * 2 + hh) * 512]);                                \
                gl_lds16(Bb + (size_t)(n0 + r) * lda + k0 + (hh << 5) + (cg << 3),  \
                         &ldsB[(b * 2 + hh) * 512]);                                \
            }                                                                       \
        }                                                                           \
    }

#define MFMA64()                                                                    \
    {                                                                               \
        _Pragma("unroll")                                                           \
        for (int hh = 0; hh < 2; hh++) {                                            \
            short8 af[4], bf[4];                                                    \
            _Pragma("unroll")                                                       \
            for (int i = 0; i < 4; i++) {                                           \
                int rr = (wm << 6) + (i << 4) + l15;                                \
                int g = q ^ ((rr >> 1) & 3);                                        \
                af[i] = *(const short8*)&ldsA[((rr >> 4) * 2 + hh) * 512 +          \
                                              (rr & 15) * 32 + (g << 3)];           \
            }                                                                       \
            _Pragma("unroll")                                                       \
            for (int j = 0; j < 4; j++) {                                           \
                int rr = (wn << 6) + (j << 4) + l15;                                \
                int g = q ^ ((rr >> 1) & 3);                                        \
                bf[j] = *(const short8*)&ldsB[((rr >> 4) * 2 + hh) * 512 +          \
                                              (rr & 15) * 32 + (g << 3)];           \
            }                                                                       \
            _Pragma("unroll")                                                       \
            for (int i = 0; i < 4; i++)                                             \
                _Pragma("unroll")                                                   \
                for (int j = 0; j < 4; j++)                                         \
                    acc[i][j] = __builtin_amdgcn_mfma_f32_16x16x32_bf16(            \
                        af[i], bf[j], acc[i][j], 0, 0, 0);                          \
        }                                                                           \
    }

// ---- merged stage-A GEMM: seg<640 routed [H|X3h], else shared (G fused silu(u)*v) ----
__global__ __launch_bounds__(256) void gemm_A(
    const u16* __restrict__ XS, const u16* __restrict__ Xb,
    const u16* __restrict__ W13, const u16* __restrict__ S12,
    const float* __restrict__ b1, const float* __restrict__ b3,
    u16* __restrict__ H, u16* __restrict__ X3h, u16* __restrict__ G,
    const int* __restrict__ tileexp, const int* __restrict__ ntiles) {
    __shared__ u16 ldsA[128 * 64];
    __shared__ u16 ldsB[128 * 64];
    int seg = blockIdx.x;
    const u16 *Ab, *Bb; int mt, nt, e = 0; bool routed;
    if (seg < 640) {
        routed = true;
        int pair = seg / 80, w80 = seg % 80;     // nt-pairing: A-tile reused at distance 40
        mt = w80 % 40; nt = pair * 2 + w80 / 40;
        if (mt >= ntiles[0]) return;
        e = tileexp[mt];
        Ab = XS; Bb = W13 + ((size_t)e << 21);
    } else {
        routed = false; int s = seg - 640;
        int pair = s / 32, w32 = s % 32;
        mt = w32 % 16; nt = pair * 2 + w32 / 16;
        Ab = Xb; Bb = S12;
    }
    int m0 = mt * 128, n0 = nt * 128;
    int tid = threadIdx.x, w = tid >> 6, lane = tid & 63;
    int wm = w >> 1, wn = w & 1;

    floatx4 acc[4][4];
#pragma unroll
    for (int i = 0; i < 4; i++)
#pragma unroll
        for (int j = 0; j < 4; j++) { floatx4 z = {0.f, 0.f, 0.f, 0.f}; acc[i][j] = z; }

    int rloc = lane >> 2, clds = lane & 3, q = lane >> 4, l15 = lane & 15;

    for (int k0 = 0; k0 < 1024; k0 += 64) {
        STAGE64(Ab, Bb, 1024);
        __syncthreads();
        MFMA64();
        __syncthreads();
    }

    if (routed) {
#pragma unroll
        for (int i = 0; i < 4; i++) {
            int rowb = m0 + (wm << 6) + (i << 4) + (q << 2);
#pragma unroll
            for (int j = 0; j < 4; j++) {
                int col = n0 + (wn << 6) + (j << 4) + l15;
#pragma unroll
                for (int r = 0; r < 4; r++) {
                    float v = acc[i][j][r];
                    int rw = rowb + r;
                    if (nt < 8) {
                        H[(size_t)rw * 1024 + col] = f2bf(silu_f(v + b1[e * 1024 + col]));
                    } else {
                        int c2 = col - 1024;
                        X3h[(size_t)rw * 1024 + c2] = f2bf(v + b3[e * 1024 + c2]);
                    }
                }
            }
        }
    } else {
#pragma unroll
        for (int i = 0; i < 4; i++) {
            int rowb = m0 + (wm << 6) + (i << 4) + (q << 2);
#pragma unroll
            for (int jp = 0; jp < 4; jp += 2) {
                int brb = n0 + (wn << 6) + (jp << 4);
                int lcol = ((brb >> 5) << 4) + l15;
#pragma unroll
                for (int r = 0; r < 4; r++) {
                    float u = acc[i][jp][r], v = acc[i][jp + 1][r];
                    G[(size_t)(rowb + r) * 2048 + lcol] = f2bf(silu_f(u) * v);
                }
            }
        }
    }
}

// ---- merged stage-B GEMM, split-K=2 ----
__global__ __launch_bounds__(256) void gemm_B(
    const u16* __restrict__ H, const u16* __restrict__ G,
    const u16* __restrict__ W2b, const u16* __restrict__ S3b,
    const float* __restrict__ b2, const u16* __restrict__ X3h,
    u16* __restrict__ P0, u16* __restrict__ P1,
    float* __restrict__ Z0, float* __restrict__ Z1,
    const int* __restrict__ tileexp, const int* __restrict__ ntiles) {
    __shared__ u16 ldsA[128 * 64];
    __shared__ u16 ldsB[128 * 64];
    int seg = blockIdx.x;
    const u16 *Ab, *Bb; int mt, nt, kc, lda, kbeg, kspan, e = 0; bool routed;
    if (seg < 640) {
        routed = true; kc = seg & 1; int s2 = seg >> 1;
        mt = s2 % 40; nt = s2 / 40;
        if (mt >= ntiles[0]) return;
        e = tileexp[mt];
        Ab = H; Bb = W2b + ((size_t)e << 20); lda = 1024; kbeg = kc << 9; kspan = 512;
    } else {
        routed = false; int s = seg - 640; kc = s & 1; int s2 = s >> 1;
        mt = s2 & 15; nt = s2 >> 4;
        Ab = G; Bb = S3b; lda = 2048; kbeg = kc << 10; kspan = 1024;
    }
    int kend = kbeg + kspan;
    int m0 = mt * 128, n0 = nt * 128;
    int tid = threadIdx.x, w = tid >> 6, lane = tid & 63;
    int wm = w >> 1, wn = w & 1;

    floatx4 acc[4][4];
#pragma unroll
    for (int i = 0; i < 4; i++)
#pragma unroll
        for (int j = 0; j < 4; j++) { floatx4 z = {0.f, 0.f, 0.f, 0.f}; acc[i][j] = z; }

    int rloc = lane >> 2, clds = lane & 3, q = lane >> 4, l15 = lane & 15;

    for (int k0 = kbeg; k0 < kend; k0 += 64) {
        STAGE64(Ab, Bb, lda);
        __syncthreads();
        MFMA64();
        __syncthreads();
    }

    if (routed) {
        u16* Pk = kc ? P1 : P0;
#pragma unroll
        for (int i = 0; i < 4; i++) {
            int rowb = m0 + (wm << 6) + (i << 4) + (q << 2);
#pragma unroll
            for (int j = 0; j < 4; j++) {
                int col = n0 + (wn << 6) + (j << 4) + l15;
#pragma unroll
                for (int r = 0; r < 4; r++) {
                    int rw = rowb + r;
                    float v = acc[i][j][r] + (kc == 0 ? b2[e * 1024 + col] : 0.f);
                    float pv = v * bf2f(X3h[(size_t)rw * 1024 + col]);
                    Pk[(size_t)rw * 1024 + col] = f2bf(pv);
                }
            }
        }
    } else {
        float* Zk = kc ? Z1 : Z0;
#pragma unroll
        for (int i = 0; i < 4; i++) {
            int rowb = m0 + (wm << 6) + (i << 4) + (q << 2);
#pragma unroll
            for (int j = 0; j < 4; j++) {
                int col = n0 + (wn << 6) + (j << 4) + l15;
#pragma unroll
                for (int r = 0; r < 4; r++)
                    Zk[(size_t)(rowb + r) * 1024 + col] = acc[i][j][r];
            }
        }
    }
}

__global__ void final_k(const float* __restrict__ Z0, const float* __restrict__ Z1,
                        const u16* __restrict__ P0, const u16* __restrict__ P1,
                        const int* __restrict__ slot_of, float* __restrict__ out) {
    int i = blockIdx.x * 256 + threadIdx.x;
    int t = i >> 8, c4 = i & 255;
    int s0 = slot_of[2 * t], s1 = slot_of[2 * t + 1];
    float4 z0 = ((const float4*)Z0)[(size_t)t * 256 + c4];
    float4 z1 = ((const float4*)Z1)[(size_t)t * 256 + c4];
    ushort4 a0 = ((const ushort4*)P0)[(size_t)s0 * 256 + c4];
    ushort4 a1 = ((const ushort4*)P1)[(size_t)s0 * 256 + c4];
    ushort4 c0 = ((const ushort4*)P0)[(size_t)s1 * 256 + c4];
    ushort4 c1 = ((const ushort4*)P1)[(size_t)s1 * 256 + c4];
    float4 o;
    o.x = z0.x + z1.x + bf2f(a0.x) + bf2f(a1.x) + bf2f(c0.x) + bf2f(c1.x);
    o.y = z0.y + z1.y + bf2f(a0.y) + bf2f(a1.y) + bf2f(c0.y) + bf2f(c1.y);
    o.z = z0.z + z1.z + bf2f(a0.z) + bf2f(a1.z) + bf2f(c0.z) + bf2f(c1.z);
    o.w = z0.w + z1.w + bf2f(a0.w) + bf2f(a1.w) + bf2f(c0.w) + bf2f(c1.w);
    ((float4*)out)[(size_t)t * 256 + c4] = o;
}

extern "C" void kernel_launch(void* const* d_in, const int* in_sizes, int n_in,
                              void* d_out, int out_size, void* d_ws, size_t ws_size,
                              hipStream_t stream) {
    const float* x   = (const float*)d_in[0];
    const float* gw  = (const float*)d_in[1];
    const float* w1  = (const float*)d_in[2];
    const float* b1  = (const float*)d_in[3];
    const float* w2  = (const float*)d_in[4];
    const float* b2  = (const float*)d_in[5];
    const float* w3  = (const float*)d_in[6];
    const float* b3  = (const float*)d_in[7];
    const float* sw1 = (const float*)d_in[8];
    const float* sw2 = (const float*)d_in[9];
    const float* sw3 = (const float*)d_in[10];
    float* out = (float*)d_out;

    char* p = (char*)d_ws;
    int* ntiles  = (int*)(p + 192);
    int* tileexp = (int*)(p + 256);
    size_t off = 4096;
    u16*   XS      = (u16*)(p + off);   off += (size_t)MAXROWS * 1024 * 2;
    int*   idxA    = (int*)(p + off);   off += 16384;
    float* wA      = (float*)(p + off); off += 16384;
    int*   slot_of = (int*)(p + off);   off += 16384;
    u16*   H       = (u16*)(p + off);   off += (size_t)MAXROWS * 1024 * 2;
    u16*   X3h     = (u16*)(p + off);   off += (size_t)MAXROWS * 1024 * 2;
    u16*   P0      = (u16*)(p + off);   off += (size_t)MAXROWS * 1024 * 2;
    u16*   P1      = (u16*)(p + off);   off += (size_t)MAXROWS * 1024 * 2;
    float* Z0      = (float*)(p + off); off += (size_t)2048 * 1024 * 4;
    float* Z1      = (float*)(p + off); off += (size_t)2048 * 1024 * 4;
    u16*   W13     = (u16*)(p + off);   off += (size_t)8 * 2048 * 1024 * 2;
    u16*   W2b     = (u16*)(p + off);   off += (size_t)8 * 1024 * 1024 * 2;
    u16*   S12     = (u16*)(p + off);   off += (size_t)4096 * 1024 * 2;
    u16*   S3b     = (u16*)(p + off);   off += (size_t)1024 * 2048 * 2;
    u16*   Xb      = (u16*)(p + off);   off += (size_t)2048 * 1024 * 2;
    u16*   G       = (u16*)(p + off);   off += (size_t)2048 * 2048 * 2;

    conv_gate<<<33280, 256, 0, stream>>>(w1, w2, w3, sw1, sw2, sw3, x, gw,
                                         W13, W2b, S12, S3b, Xb, idxA, wA);
    rank_k<<<1, 64, 0, stream>>>(idxA, tileexp, ntiles, slot_of);
    build_xs<<<4096, 256, 0, stream>>>(x, wA, slot_of, XS);

    gemm_A<<<1152, 256, 0, stream>>>(XS, Xb, W13, S12, b1, b3, H, X3h, G,
                                     tileexp, ntiles);
    gemm_B<<<896, 256, 0, stream>>>(H, G, W2b, S3b, b2, X3h, P0, P1, Z0, Z1,
                                    tileexp, ntiles);
    final_k<<<2048, 256, 0, stream>>>(Z0, Z1, P0, P1, slot_of, out);
}

// Round 5
// 316.067 us; speedup vs baseline: 1.2970x; 1.0201x over previous
//
#include <hip/hip_runtime.h>

typedef unsigned short u16;
typedef __attribute__((ext_vector_type(4))) float floatx4;
typedef __attribute__((ext_vector_type(8))) short short8;

#define MAXROWS 5120   // 4096 slots + 8*128 padding
#define MAXMT 40

__device__ __forceinline__ u16 f2bf(float f) {
    union { float f; unsigned u; } v; v.f = f;
    unsigned r = v.u + 0x7FFF + ((v.u >> 16) & 1);
    return (u16)(r >> 16);
}
__device__ __forceinline__ float bf2f(u16 h) {
    union { unsigned u; float f; } v; v.u = ((unsigned)h) << 16; return v.f;
}
__device__ __forceinline__ float silu_f(float x) { return x / (1.f + __expf(-x)); }

__device__ __forceinline__ void gl_lds16(const void* g, void* l) {
    __builtin_amdgcn_global_load_lds(
        (__attribute__((address_space(1))) unsigned int*)g,
        (__attribute__((address_space(3))) unsigned int*)l, 16, 0, 0);
}

// ---- fused: gate (blocks 0..511) + fp32->bf16 conversion ----
// S12 layout: 32-row groups: rows g*32+0..15 = sw1[g*16..], g*32+16..31 = sw2[g*16..]
__global__ void conv_gate(const float* __restrict__ w1, const float* __restrict__ w2,
                          const float* __restrict__ w3, const float* __restrict__ sw1,
                          const float* __restrict__ sw2, const float* __restrict__ sw3,
                          const float* __restrict__ x, const float* __restrict__ gw,
                          u16* __restrict__ W13, u16* __restrict__ W2b,
                          u16* __restrict__ S12, u16* __restrict__ S3b,
                          u16* __restrict__ Xb,
                          int* __restrict__ idxA, float* __restrict__ wA) {
    int bid = blockIdx.x;
    if (bid < 512) {  // ---- gate ----
        int w = threadIdx.x >> 6, lane = threadIdx.x & 63;
        int t = bid * 4 + w;
        const float* xr = x + (size_t)t * 1024;
        float acc[8];
#pragma unroll
        for (int e = 0; e < 8; e++) acc[e] = 0.f;
#pragma unroll
        for (int i = 0; i < 16; i++) {
            float xv = xr[lane + (i << 6)];
#pragma unroll
            for (int e = 0; e < 8; e++) acc[e] += xv * gw[e * 1024 + lane + (i << 6)];
        }
#pragma unroll
        for (int e = 0; e < 8; e++)
            for (int off = 32; off > 0; off >>= 1) acc[e] += __shfl_xor(acc[e], off);
        if (lane == 0) {
            float m = acc[0];
#pragma unroll
            for (int e = 1; e < 8; e++) m = fmaxf(m, acc[e]);
            float p[8], s = 0.f;
#pragma unroll
            for (int e = 0; e < 8; e++) { p[e] = __expf(acc[e] - m); s += p[e]; }
            float inv = 1.f / s;
#pragma unroll
            for (int e = 0; e < 8; e++) p[e] *= inv;
            int i0 = 0;
#pragma unroll
            for (int e = 1; e < 8; e++) if (p[e] > p[i0]) i0 = e;
            int i1 = (i0 == 0) ? 1 : 0;
            for (int e = i1 + 1; e < 8; e++) if (e != i0 && p[e] > p[i1]) i1 = e;
            idxA[2 * t] = i0; idxA[2 * t + 1] = i1;
            wA[2 * t] = p[i0]; wA[2 * t + 1] = p[i1];
        }
        return;
    }
    long j = (long)(bid - 512) * 256 + threadIdx.x;
    const float* src; u16* dst; long d;
    if (j < 2097152) {
        long e = j >> 18; src = w1; dst = W13; d = j + (e << 18);
    } else if ((j -= 2097152) < 2097152) {
        long e = j >> 18; src = w3; dst = W13; d = j + (e << 18) + 262144;
    } else if ((j -= 2097152) < 2097152) { src = w2;  dst = W2b; d = j; }
    else if ((j -= 2097152) < 524288) {
        long rr = j >> 8, c4 = j & 255;
        long br = ((rr >> 4) << 5) + (rr & 15);
        src = sw1; dst = S12; d = (br << 8) + c4;
    } else if ((j -= 524288) < 524288) {
        long rr = j >> 8, c4 = j & 255;
        long br = ((rr >> 4) << 5) + 16 + (rr & 15);
        src = sw2; dst = S12; d = (br << 8) + c4;
    } else if ((j -= 524288) < 524288)     { src = sw3; dst = S3b; d = j; }
    else { j -= 524288; src = x; dst = Xb; d = j; }
    float4 v = ((const float4*)src)[j];
    ushort4 o; o.x = f2bf(v.x); o.y = f2bf(v.y); o.z = f2bf(v.z); o.w = f2bf(v.w);
    ((ushort4*)dst)[d] = o;
}

// ---- single-wave deterministic rank/scatter (0 atomics) ----
__global__ void rank_k(const int* __restrict__ idxA, int* __restrict__ tileexp,
                       int* __restrict__ ntiles, int* __restrict__ slot_of) {
    int lane = threadIdx.x;
    const int* my = idxA + lane * 64;
    int h[8];
#pragma unroll
    for (int e = 0; e < 8; e++) h[e] = 0;
    for (int i = 0; i < 64; i++) {
        int v = my[i];
#pragma unroll
        for (int e = 0; e < 8; e++) h[e] += (v == e);
    }
    int excl[8], tot[8];
#pragma unroll
    for (int e = 0; e < 8; e++) {
        int inc = h[e];
        for (int off = 1; off < 64; off <<= 1) {
            int up = __shfl_up(inc, off);
            if (lane >= off) inc += up;
        }
        excl[e] = inc - h[e];
        tot[e] = __shfl(inc, 63);
    }
    int base[8], tiles = 0;
#pragma unroll
    for (int e = 0; e < 8; e++) {
        base[e] = tiles * 128;
        tiles += (tot[e] + 127) >> 7;
    }
    if (lane == 0) {
        ntiles[0] = tiles;
        int t = 0;
        for (int e = 0; e < 8; e++) {
            int te = (tot[e] + 127) >> 7;
            for (int j = 0; j < te; j++) tileexp[t++] = e;
        }
    }
    int c[8];
#pragma unroll
    for (int e = 0; e < 8; e++) c[e] = base[e] + excl[e];
    for (int i = 0; i < 64; i++) {
        int v = my[i], slot = 0;
#pragma unroll
        for (int e = 0; e < 8; e++) slot += (v == e) ? c[e] : 0;
#pragma unroll
        for (int e = 0; e < 8; e++) c[e] += (v == e);
        slot_of[lane * 64 + i] = slot;
    }
}

__global__ void build_xs(const float* __restrict__ x, const float* __restrict__ wA,
                         const int* __restrict__ slot_of, u16* __restrict__ XS) {
    int s = blockIdx.x, i = threadIdx.x;
    int t = s >> 1; float w = wA[s]; int slot = slot_of[s];
    float4 v = ((const float4*)(x + (size_t)t * 1024))[i];
    ushort4 o; o.x = f2bf(v.x * w); o.y = f2bf(v.y * w); o.z = f2bf(v.z * w); o.w = f2bf(v.w * w);
    ((ushort4*)(XS + (size_t)slot * 1024))[i] = o;
}

// ======== BK=64 GEMM core ========
#define STAGE64(Ab, Bb, lda)                                                        \
    {                                                                               \
        _Pragma("unroll")                                                           \
        for (int t = 0; t < 2; t++) {                                               \
            int b = w + (t << 2);                                                   \
            int r = (b << 4) + rloc;                                                \
            int cg = clds ^ ((r >> 1) & 3);                                         \
            _Pragma("unroll")                                                       \
            for (int hh = 0; hh < 2; hh++) {                                        \
                gl_lds16(Ab + (size_t)(m0 + r) * lda + k0 + (hh << 5) + (cg << 3),  \
                         &ldsA[(b * 2 + hh) * 512]);                                \
                gl_lds16(Bb + (size_t)(n0 + r) * lda + k0 + (hh << 5) + (cg << 3),  \
                         &ldsB[(b * 2 + hh) * 512]);                                \
            }                                                                       \
        }                                                                           \
    }

#define MFMA64()                                                                    \
    {                                                                               \
        _Pragma("unroll")                                                           \
        for (int hh = 0; hh < 2; hh++) {                                            \
            short8 af[4], bf[4];                                                    \
            _Pragma("unroll")                                                       \
            for (int i = 0; i < 4; i++) {                                           \
                int rr = (wm << 6) + (i << 4) + l15;                                \
                int g = q ^ ((rr >> 1) & 3);                                        \
                af[i] = *(const short8*)&ldsA[((rr >> 4) * 2 + hh) * 512 +          \
                                              (rr & 15) * 32 + (g << 3)];           \
            }                                                                       \
            _Pragma("unroll")                                                       \
            for (int j = 0; j < 4; j++) {                                           \
                int rr = (wn << 6) + (j << 4) + l15;                                \
                int g = q ^ ((rr >> 1) & 3);                                        \
                bf[j] = *(const short8*)&ldsB[((rr >> 4) * 2 + hh) * 512 +          \
                                              (rr & 15) * 32 + (g << 3)];           \
            }                                                                       \
            _Pragma("unroll")                                                       \
            for (int i = 0; i < 4; i++)                                             \
                _Pragma("unroll")                                                   \
                for (int j = 0; j < 4; j++)                                         \
                    acc[i][j] = __builtin_amdgcn_mfma_f32_16x16x32_bf16(            \
                        af[i], bf[j], acc[i][j], 0, 0, 0);                          \
        }                                                                           \
    }

// ---- merged stage-A GEMM, XCD-partitioned (blockIdx%8 = XCD heuristic) ----
// XCD x: routed mt in {5x..5x+4} (contiguous -> 1-2 experts' W13 only);
//        shared (mtg = x>>2, ntg = x&3): mt in [mtg*8, +8), nt in [ntg*8, +8).
__global__ __launch_bounds__(256) void gemm_A(
    const u16* __restrict__ XS, const u16* __restrict__ Xb,
    const u16* __restrict__ W13, const u16* __restrict__ S12,
    const float* __restrict__ b1, const float* __restrict__ b3,
    u16* __restrict__ H, u16* __restrict__ X3h, u16* __restrict__ G,
    const int* __restrict__ tileexp, const int* __restrict__ ntiles) {
    __shared__ u16 ldsA[128 * 64];
    __shared__ u16 ldsB[128 * 64];
    int xcd = blockIdx.x & 7, ws = blockIdx.x >> 3;   // ws in [0,144)
    const u16 *Ab, *Bb; int mt, nt, e = 0; bool routed;
    if (ws < 80) {
        routed = true;
        mt = xcd * 5 + (ws >> 4);       // mt-major: consecutive ws share mt
        nt = ws & 15;
        if (mt >= ntiles[0]) return;
        e = tileexp[mt];
        Ab = XS; Bb = W13 + ((size_t)e << 21);
    } else {
        routed = false; int s = ws - 80;               // [0,64)
        mt = ((xcd >> 2) << 3) + (s >> 3);             // [0,16)
        nt = ((xcd & 3) << 3) + (s & 7);               // [0,32)
        Ab = Xb; Bb = S12;
    }
    int m0 = mt * 128, n0 = nt * 128;
    int tid = threadIdx.x, w = tid >> 6, lane = tid & 63;
    int wm = w >> 1, wn = w & 1;

    floatx4 acc[4][4];
#pragma unroll
    for (int i = 0; i < 4; i++)
#pragma unroll
        for (int j = 0; j < 4; j++) { floatx4 z = {0.f, 0.f, 0.f, 0.f}; acc[i][j] = z; }

    int rloc = lane >> 2, clds = lane & 3, q = lane >> 4, l15 = lane & 15;

    for (int k0 = 0; k0 < 1024; k0 += 64) {
        STAGE64(Ab, Bb, 1024);
        __syncthreads();
        MFMA64();
        __syncthreads();
    }

    if (routed) {
#pragma unroll
        for (int i = 0; i < 4; i++) {
            int rowb = m0 + (wm << 6) + (i << 4) + (q << 2);
#pragma unroll
            for (int j = 0; j < 4; j++) {
                int col = n0 + (wn << 6) + (j << 4) + l15;
#pragma unroll
                for (int r = 0; r < 4; r++) {
                    float v = acc[i][j][r];
                    int rw = rowb + r;
                    if (nt < 8) {
                        H[(size_t)rw * 1024 + col] = f2bf(silu_f(v + b1[e * 1024 + col]));
                    } else {
                        int c2 = col - 1024;
                        X3h[(size_t)rw * 1024 + c2] = f2bf(v + b3[e * 1024 + c2]);
                    }
                }
            }
        }
    } else {
#pragma unroll
        for (int i = 0; i < 4; i++) {
            int rowb = m0 + (wm << 6) + (i << 4) + (q << 2);
#pragma unroll
            for (int jp = 0; jp < 4; jp += 2) {
                int brb = n0 + (wn << 6) + (jp << 4);
                int lcol = ((brb >> 5) << 4) + l15;
#pragma unroll
                for (int r = 0; r < 4; r++) {
                    float u = acc[i][jp][r], v = acc[i][jp + 1][r];
                    G[(size_t)(rowb + r) * 2048 + lcol] = f2bf(silu_f(u) * v);
                }
            }
        }
    }
}

// ---- merged stage-B GEMM, split-K=2, XCD-partitioned ----
// XCD x: routed mt in {5x..5x+4}, all nt(8) x kc(2);
//        shared (mtg = x>>1, ntg = x&1): mt in [mtg*4,+4), nt in [ntg*4,+4), kc 2.
__global__ __launch_bounds__(256) void gemm_B(
    const u16* __restrict__ H, const u16* __restrict__ G,
    const u16* __restrict__ W2b, const u16* __restrict__ S3b,
    const float* __restrict__ b2, const u16* __restrict__ X3h,
    u16* __restrict__ P0, u16* __restrict__ P1,
    float* __restrict__ Z0, float* __restrict__ Z1,
    const int* __restrict__ tileexp, const int* __restrict__ ntiles) {
    __shared__ u16 ldsA[128 * 64];
    __shared__ u16 ldsB[128 * 64];
    int xcd = blockIdx.x & 7, ws = blockIdx.x >> 3;   // ws in [0,112)
    const u16 *Ab, *Bb; int mt, nt, kc, lda, kbeg, kspan, e = 0; bool routed;
    if (ws < 80) {
        routed = true;
        mt = xcd * 5 + (ws >> 4);
        int r = ws & 15; nt = r & 7; kc = r >> 3;
        if (mt >= ntiles[0]) return;
        e = tileexp[mt];
        Ab = H; Bb = W2b + ((size_t)e << 20); lda = 1024; kbeg = kc << 9; kspan = 512;
    } else {
        routed = false; int s = ws - 80;               // [0,32)
        kc = s & 1; int s2 = s >> 1;                   // [0,16)
        mt = ((xcd >> 1) << 2) + (s2 >> 2);            // [0,16)
        nt = ((xcd & 1) << 2) + (s2 & 3);              // [0,8)
        Ab = G; Bb = S3b; lda = 2048; kbeg = kc << 10; kspan = 1024;
    }
    int kend = kbeg + kspan;
    int m0 = mt * 128, n0 = nt * 128;
    int tid = threadIdx.x, w = tid >> 6, lane = tid & 63;
    int wm = w >> 1, wn = w & 1;

    floatx4 acc[4][4];
#pragma unroll
    for (int i = 0; i < 4; i++)
#pragma unroll
        for (int j = 0; j < 4; j++) { floatx4 z = {0.f, 0.f, 0.f, 0.f}; acc[i][j] = z; }

    int rloc = lane >> 2, clds = lane & 3, q = lane >> 4, l15 = lane & 15;

    for (int k0 = kbeg; k0 < kend; k0 += 64) {
        STAGE64(Ab, Bb, lda);
        __syncthreads();
        MFMA64();
        __syncthreads();
    }

    if (routed) {
        u16* Pk = kc ? P1 : P0;
#pragma unroll
        for (int i = 0; i < 4; i++) {
            int rowb = m0 + (wm << 6) + (i << 4) + (q << 2);
#pragma unroll
            for (int j = 0; j < 4; j++) {
                int col = n0 + (wn << 6) + (j << 4) + l15;
#pragma unroll
                for (int r = 0; r < 4; r++) {
                    int rw = rowb + r;
                    float v = acc[i][j][r] + (kc == 0 ? b2[e * 1024 + col] : 0.f);
                    float pv = v * bf2f(X3h[(size_t)rw * 1024 + col]);
                    Pk[(size_t)rw * 1024 + col] = f2bf(pv);
                }
            }
        }
    } else {
        float* Zk = kc ? Z1 : Z0;
#pragma unroll
        for (int i = 0; i < 4; i++) {
            int rowb = m0 + (wm << 6) + (i << 4) + (q << 2);
#pragma unroll
            for (int j = 0; j < 4; j++) {
                int col = n0 + (wn << 6) + (j << 4) + l15;
#pragma unroll
                for (int r = 0; r < 4; r++)
                    Zk[(size_t)(rowb + r) * 1024 + col] = acc[i][j][r];
            }
        }
    }
}

__global__ void final_k(const float* __restrict__ Z0, const float* __restrict__ Z1,
                        const u16* __restrict__ P0, const u16* __restrict__ P1,
                        const int* __restrict__ slot_of, float* __restrict__ out) {
    int i = blockIdx.x * 256 + threadIdx.x;
    int t = i >> 8, c4 = i & 255;
    int s0 = slot_of[2 * t], s1 = slot_of[2 * t + 1];
    float4 z0 = ((const float4*)Z0)[(size_t)t * 256 + c4];
    float4 z1 = ((const float4*)Z1)[(size_t)t * 256 + c4];
    ushort4 a0 = ((const ushort4*)P0)[(size_t)s0 * 256 + c4];
    ushort4 a1 = ((const ushort4*)P1)[(size_t)s0 * 256 + c4];
    ushort4 c0 = ((const ushort4*)P0)[(size_t)s1 * 256 + c4];
    ushort4 c1 = ((const ushort4*)P1)[(size_t)s1 * 256 + c4];
    float4 o;
    o.x = z0.x + z1.x + bf2f(a0.x) + bf2f(a1.x) + bf2f(c0.x) + bf2f(c1.x);
    o.y = z0.y + z1.y + bf2f(a0.y) + bf2f(a1.y) + bf2f(c0.y) + bf2f(c1.y);
    o.z = z0.z + z1.z + bf2f(a0.z) + bf2f(a1.z) + bf2f(c0.z) + bf2f(c1.z);
    o.w = z0.w + z1.w + bf2f(a0.w) + bf2f(a1.w) + bf2f(c0.w) + bf2f(c1.w);
    ((float4*)out)[(size_t)t * 256 + c4] = o;
}

extern "C" void kernel_launch(void* const* d_in, const int* in_sizes, int n_in,
                              void* d_out, int out_size, void* d_ws, size_t ws_size,
                              hipStream_t stream) {
    const float* x   = (const float*)d_in[0];
    const float* gw  = (const float*)d_in[1];
    const float* w1  = (const float*)d_in[2];
    const float* b1  = (const float*)d_in[3];
    const float* w2  = (const float*)d_in[4];
    const float* b2  = (const float*)d_in[5];
    const float* w3  = (const float*)d_in[6];
    const float* b3  = (const float*)d_in[7];
    const float* sw1 = (const float*)d_in[8];
    const float* sw2 = (const float*)d_in[9];
    const float* sw3 = (const float*)d_in[10];
    float* out = (float*)d_out;

    char* p = (char*)d_ws;
    int* ntiles  = (int*)(p + 192);
    int* tileexp = (int*)(p + 256);
    size_t off = 4096;
    u16*   XS      = (u16*)(p + off);   off += (size_t)MAXROWS * 1024 * 2;
    int*   idxA    = (int*)(p + off);   off += 16384;
    float* wA      = (float*)(p + off); off += 16384;
    int*   slot_of = (int*)(p + off);   off += 16384;
    u16*   H       = (u16*)(p + off);   off += (size_t)MAXROWS * 1024 * 2;
    u16*   X3h     = (u16*)(p + off);   off += (size_t)MAXROWS * 1024 * 2;
    u16*   P0      = (u16*)(p + off);   off += (size_t)MAXROWS * 1024 * 2;
    u16*   P1      = (u16*)(p + off);   off += (size_t)MAXROWS * 1024 * 2;
    float* Z0      = (float*)(p + off); off += (size_t)2048 * 1024 * 4;
    float* Z1      = (float*)(p + off); off += (size_t)2048 * 1024 * 4;
    u16*   W13     = (u16*)(p + off);   off += (size_t)8 * 2048 * 1024 * 2;
    u16*   W2b     = (u16*)(p + off);   off += (size_t)8 * 1024 * 1024 * 2;
    u16*   S12     = (u16*)(p + off);   off += (size_t)4096 * 1024 * 2;
    u16*   S3b     = (u16*)(p + off);   off += (size_t)1024 * 2048 * 2;
    u16*   Xb      = (u16*)(p + off);   off += (size_t)2048 * 1024 * 2;
    u16*   G       = (u16*)(p + off);   off += (size_t)2048 * 2048 * 2;

    conv_gate<<<33280, 256, 0, stream>>>(w1, w2, w3, sw1, sw2, sw3, x, gw,
                                         W13, W2b, S12, S3b, Xb, idxA, wA);
    rank_k<<<1, 64, 0, stream>>>(idxA, tileexp, ntiles, slot_of);
    build_xs<<<4096, 256, 0, stream>>>(x, wA, slot_of, XS);

    gemm_A<<<1152, 256, 0, stream>>>(XS, Xb, W13, S12, b1, b3, H, X3h, G,
                                     tileexp, ntiles);
    gemm_B<<<896, 256, 0, stream>>>(H, G, W2b, S3b, b2, X3h, P0, P1, Z0, Z1,
                                    tileexp, ntiles);
    final_k<<<2048, 256, 0, stream>>>(Z0, Z1, P0, P1, slot_of, out);
}

// Round 6
// 310.690 us; speedup vs baseline: 1.3195x; 1.0173x over previous
//
#include <hip/hip_runtime.h>

typedef unsigned short u16;
typedef __attribute__((ext_vector_type(4))) float floatx4;
typedef __attribute__((ext_vector_type(8))) short short8;

#define MAXROWS 5120   // 4096 slots + 8*128 padding
#define MAXMT 40

__device__ __forceinline__ u16 f2bf(float f) {
    union { float f; unsigned u; } v; v.f = f;
    unsigned r = v.u + 0x7FFF + ((v.u >> 16) & 1);
    return (u16)(r >> 16);
}
__device__ __forceinline__ float bf2f(u16 h) {
    union { unsigned u; float f; } v; v.u = ((unsigned)h) << 16; return v.f;
}
__device__ __forceinline__ float silu_f(float x) { return x / (1.f + __expf(-x)); }

__device__ __forceinline__ void gl_lds16(const void* g, void* l) {
    __builtin_amdgcn_global_load_lds(
        (__attribute__((address_space(1))) unsigned int*)g,
        (__attribute__((address_space(3))) unsigned int*)l, 16, 0, 0);
}

// 8x ds_read_b128 + lgkmcnt(0) fused in one opaque asm block: the compiler's
// waitcnt pass cannot see LDS deps here, so it cannot inject vmcnt(0) drains.
__device__ __forceinline__ void ld_frags(
    unsigned a0, unsigned a1, unsigned a2, unsigned a3,
    unsigned b0, unsigned b1, unsigned b2, unsigned b3,
    short8& af0, short8& af1, short8& af2, short8& af3,
    short8& bf0, short8& bf1, short8& bf2, short8& bf3) {
    asm volatile(
        "ds_read_b128 %0, %8\n\t"
        "ds_read_b128 %1, %9\n\t"
        "ds_read_b128 %2, %10\n\t"
        "ds_read_b128 %3, %11\n\t"
        "ds_read_b128 %4, %12\n\t"
        "ds_read_b128 %5, %13\n\t"
        "ds_read_b128 %6, %14\n\t"
        "ds_read_b128 %7, %15\n\t"
        "s_waitcnt lgkmcnt(0)"
        : "=&v"(af0), "=&v"(af1), "=&v"(af2), "=&v"(af3),
          "=&v"(bf0), "=&v"(bf1), "=&v"(bf2), "=&v"(bf3)
        : "v"(a0), "v"(a1), "v"(a2), "v"(a3),
          "v"(b0), "v"(b1), "v"(b2), "v"(b3));
}

#define WAIT_VM4() __builtin_amdgcn_s_waitcnt(3956)  // vmcnt(4), lgkm/exp no-wait
#define WAIT_VM0() __builtin_amdgcn_s_waitcnt(3952)  // vmcnt(0)
#define BAR()      __builtin_amdgcn_s_barrier()

// ---- fused: gate (blocks 0..511) + fp32->bf16 conversion ----
// S12 layout: 32-row groups: rows g*32+0..15 = sw1[g*16..], g*32+16..31 = sw2[g*16..]
__global__ void conv_gate(const float* __restrict__ w1, const float* __restrict__ w2,
                          const float* __restrict__ w3, const float* __restrict__ sw1,
                          const float* __restrict__ sw2, const float* __restrict__ sw3,
                          const float* __restrict__ x, const float* __restrict__ gw,
                          u16* __restrict__ W13, u16* __restrict__ W2b,
                          u16* __restrict__ S12, u16* __restrict__ S3b,
                          u16* __restrict__ Xb,
                          int* __restrict__ idxA, float* __restrict__ wA) {
    int bid = blockIdx.x;
    if (bid < 512) {  // ---- gate ----
        int w = threadIdx.x >> 6, lane = threadIdx.x & 63;
        int t = bid * 4 + w;
        const float* xr = x + (size_t)t * 1024;
        float acc[8];
#pragma unroll
        for (int e = 0; e < 8; e++) acc[e] = 0.f;
#pragma unroll
        for (int i = 0; i < 16; i++) {
            float xv = xr[lane + (i << 6)];
#pragma unroll
            for (int e = 0; e < 8; e++) acc[e] += xv * gw[e * 1024 + lane + (i << 6)];
        }
#pragma unroll
        for (int e = 0; e < 8; e++)
            for (int off = 32; off > 0; off >>= 1) acc[e] += __shfl_xor(acc[e], off);
        if (lane == 0) {
            float m = acc[0];
#pragma unroll
            for (int e = 1; e < 8; e++) m = fmaxf(m, acc[e]);
            float p[8], s = 0.f;
#pragma unroll
            for (int e = 0; e < 8; e++) { p[e] = __expf(acc[e] - m); s += p[e]; }
            float inv = 1.f / s;
#pragma unroll
            for (int e = 0; e < 8; e++) p[e] *= inv;
            int i0 = 0;
#pragma unroll
            for (int e = 1; e < 8; e++) if (p[e] > p[i0]) i0 = e;
            int i1 = (i0 == 0) ? 1 : 0;
            for (int e = i1 + 1; e < 8; e++) if (e != i0 && p[e] > p[i1]) i1 = e;
            idxA[2 * t] = i0; idxA[2 * t + 1] = i1;
            wA[2 * t] = p[i0]; wA[2 * t + 1] = p[i1];
        }
        return;
    }
    long j = (long)(bid - 512) * 256 + threadIdx.x;
    const float* src; u16* dst; long d;
    if (j < 2097152) {
        long e = j >> 18; src = w1; dst = W13; d = j + (e << 18);
    } else if ((j -= 2097152) < 2097152) {
        long e = j >> 18; src = w3; dst = W13; d = j + (e << 18) + 262144;
    } else if ((j -= 2097152) < 2097152) { src = w2;  dst = W2b; d = j; }
    else if ((j -= 2097152) < 524288) {
        long rr = j >> 8, c4 = j & 255;
        long br = ((rr >> 4) << 5) + (rr & 15);
        src = sw1; dst = S12; d = (br << 8) + c4;
    } else if ((j -= 524288) < 524288) {
        long rr = j >> 8, c4 = j & 255;
        long br = ((rr >> 4) << 5) + 16 + (rr & 15);
        src = sw2; dst = S12; d = (br << 8) + c4;
    } else if ((j -= 524288) < 524288)     { src = sw3; dst = S3b; d = j; }
    else { j -= 524288; src = x; dst = Xb; d = j; }
    float4 v = ((const float4*)src)[j];
    ushort4 o; o.x = f2bf(v.x); o.y = f2bf(v.y); o.z = f2bf(v.z); o.w = f2bf(v.w);
    ((ushort4*)dst)[d] = o;
}

// ---- single-wave deterministic rank/scatter (0 atomics) ----
__global__ void rank_k(const int* __restrict__ idxA, int* __restrict__ tileexp,
                       int* __restrict__ ntiles, int* __restrict__ slot_of) {
    int lane = threadIdx.x;
    const int* my = idxA + lane * 64;
    int h[8];
#pragma unroll
    for (int e = 0; e < 8; e++) h[e] = 0;
    for (int i = 0; i < 64; i++) {
        int v = my[i];
#pragma unroll
        for (int e = 0; e < 8; e++) h[e] += (v == e);
    }
    int excl[8], tot[8];
#pragma unroll
    for (int e = 0; e < 8; e++) {
        int inc = h[e];
        for (int off = 1; off < 64; off <<= 1) {
            int up = __shfl_up(inc, off);
            if (lane >= off) inc += up;
        }
        excl[e] = inc - h[e];
        tot[e] = __shfl(inc, 63);
    }
    int base[8], tiles = 0;
#pragma unroll
    for (int e = 0; e < 8; e++) {
        base[e] = tiles * 128;
        tiles += (tot[e] + 127) >> 7;
    }
    if (lane == 0) {
        ntiles[0] = tiles;
        int t = 0;
        for (int e = 0; e < 8; e++) {
            int te = (tot[e] + 127) >> 7;
            for (int j = 0; j < te; j++) tileexp[t++] = e;
        }
    }
    int c[8];
#pragma unroll
    for (int e = 0; e < 8; e++) c[e] = base[e] + excl[e];
    for (int i = 0; i < 64; i++) {
        int v = my[i], slot = 0;
#pragma unroll
        for (int e = 0; e < 8; e++) slot += (v == e) ? c[e] : 0;
#pragma unroll
        for (int e = 0; e < 8; e++) c[e] += (v == e);
        slot_of[lane * 64 + i] = slot;
    }
}

__global__ void build_xs(const float* __restrict__ x, const float* __restrict__ wA,
                         const int* __restrict__ slot_of, u16* __restrict__ XS) {
    int s = blockIdx.x, i = threadIdx.x;
    int t = s >> 1; float w = wA[s]; int slot = slot_of[s];
    float4 v = ((const float4*)(x + (size_t)t * 1024))[i];
    ushort4 o; o.x = f2bf(v.x * w); o.y = f2bf(v.y * w); o.z = f2bf(v.z * w); o.w = f2bf(v.w * w);
    ((ushort4*)(XS + (size_t)slot * 1024))[i] = o;
}

// ======== double-buffered BK=32 core, raw barriers, vmcnt(4) prefetch ========
// LDS u16 layout: A0 [0,4096) A1 [4096,8192) B0 [8192,12288) B1 [12288,16384)
// byte offsets:   A: buf*8192 ; B: 16384 + buf*8192
#define STAGE32(BUF, Ab, Bb, lda, kk)                                          \
    {                                                                          \
        _Pragma("unroll")                                                      \
        for (int t = 0; t < 2; t++) {                                          \
            int r = (w << 4) + (t << 6) + rloc;                                \
            int cg = clds ^ ((r >> 1) & 3);                                    \
            gl_lds16(Ab + (size_t)(m0 + r) * (lda) + (kk) + (cg << 3),         \
                     LDS + (BUF)*4096 + ((w << 4) + (t << 6)) * 32);           \
            gl_lds16(Bb + (size_t)(n0 + r) * (lda) + (kk) + (cg << 3),         \
                     LDS + 8192 + (BUF)*4096 + ((w << 4) + (t << 6)) * 32);    \
        }                                                                      \
    }

#define COMPUTE32(BUF)                                                         \
    {                                                                          \
        short8 af[4], bf[4];                                                   \
        ld_frags(adA[0] + (BUF)*8192, adA[1] + (BUF)*8192,                     \
                 adA[2] + (BUF)*8192, adA[3] + (BUF)*8192,                     \
                 adB[0] + (BUF)*8192, adB[1] + (BUF)*8192,                     \
                 adB[2] + (BUF)*8192, adB[3] + (BUF)*8192,                     \
                 af[0], af[1], af[2], af[3], bf[0], bf[1], bf[2], bf[3]);      \
        _Pragma("unroll")                                                      \
        for (int i = 0; i < 4; i++)                                            \
            _Pragma("unroll")                                                  \
            for (int j = 0; j < 4; j++)                                        \
                acc[i][j] = __builtin_amdgcn_mfma_f32_16x16x32_bf16(           \
                    af[i], bf[j], acc[i][j], 0, 0, 0);                         \
    }

#define KLOOP(NP, Ab, Bb, lda, kbeg)                                           \
    {                                                                          \
        STAGE32(0, Ab, Bb, lda, (kbeg));                                       \
        for (int ii = 0; ii < (NP); ii++) {                                    \
            int kk = (kbeg) + (ii << 6);                                       \
            STAGE32(1, Ab, Bb, lda, kk + 32);                                  \
            WAIT_VM4(); BAR();                                                 \
            COMPUTE32(0);                                                      \
            BAR();                                                             \
            if (ii + 1 < (NP)) {                                               \
                STAGE32(0, Ab, Bb, lda, kk + 64);                              \
                WAIT_VM4();                                                    \
            } else {                                                           \
                WAIT_VM0();                                                    \
            }                                                                  \
            BAR();                                                             \
            COMPUTE32(1);                                                      \
            BAR();                                                             \
        }                                                                      \
    }

#define GEMM_PRE()                                                             \
    int tid = threadIdx.x, w = tid >> 6, lane = tid & 63;                      \
    int wm = w >> 1, wn = w & 1;                                               \
    int rloc = lane >> 2, clds = lane & 3, q = lane >> 4, l15 = lane & 15;     \
    unsigned ldsbase = (unsigned)(size_t)(__attribute__((address_space(3))) u16*)LDS; \
    unsigned adA[4], adB[4];                                                   \
    _Pragma("unroll")                                                          \
    for (int i = 0; i < 4; i++) {                                              \
        int rr = (wm << 6) + (i << 4) + l15;                                   \
        int g = q ^ ((rr >> 1) & 3);                                           \
        adA[i] = ldsbase + rr * 64 + g * 16;                                   \
    }                                                                          \
    _Pragma("unroll")                                                          \
    for (int j = 0; j < 4; j++) {                                              \
        int rr = (wn << 6) + (j << 4) + l15;                                   \
        int g = q ^ ((rr >> 1) & 3);                                           \
        adB[j] = ldsbase + 16384 + rr * 64 + g * 16;                           \
    }                                                                          \
    floatx4 acc[4][4];                                                         \
    _Pragma("unroll")                                                          \
    for (int i = 0; i < 4; i++)                                                \
        _Pragma("unroll")                                                      \
        for (int j = 0; j < 4; j++) {                                          \
            floatx4 z = {0.f, 0.f, 0.f, 0.f}; acc[i][j] = z;                   \
        }

// ---- merged stage-A GEMM, XCD-partitioned ----
__global__ __launch_bounds__(256) void gemm_A(
    const u16* __restrict__ XS, const u16* __restrict__ Xb,
    const u16* __restrict__ W13, const u16* __restrict__ S12,
    const float* __restrict__ b1, const float* __restrict__ b3,
    u16* __restrict__ H, u16* __restrict__ X3h, u16* __restrict__ G,
    const int* __restrict__ tileexp, const int* __restrict__ ntiles) {
    __shared__ u16 LDS[16384];
    int xcd = blockIdx.x & 7, ws = blockIdx.x >> 3;   // ws in [0,144)
    const u16 *Ab, *Bb; int mt, nt, e = 0; bool routed;
    if (ws < 80) {
        routed = true;
        mt = xcd * 5 + (ws >> 4);
        nt = ws & 15;
        if (mt >= ntiles[0]) return;
        e = tileexp[mt];
        Ab = XS; Bb = W13 + ((size_t)e << 21);
    } else {
        routed = false; int s = ws - 80;
        mt = ((xcd >> 2) << 3) + (s >> 3);
        nt = ((xcd & 3) << 3) + (s & 7);
        Ab = Xb; Bb = S12;
    }
    int m0 = mt * 128, n0 = nt * 128;
    GEMM_PRE();

    KLOOP(16, Ab, Bb, 1024, 0);

    if (routed) {
#pragma unroll
        for (int i = 0; i < 4; i++) {
            int rowb = m0 + (wm << 6) + (i << 4) + (q << 2);
#pragma unroll
            for (int j = 0; j < 4; j++) {
                int col = n0 + (wn << 6) + (j << 4) + l15;
#pragma unroll
                for (int r = 0; r < 4; r++) {
                    float v = acc[i][j][r];
                    int rw = rowb + r;
                    if (nt < 8) {
                        H[(size_t)rw * 1024 + col] = f2bf(silu_f(v + b1[e * 1024 + col]));
                    } else {
                        int c2 = col - 1024;
                        X3h[(size_t)rw * 1024 + c2] = f2bf(v + b3[e * 1024 + c2]);
                    }
                }
            }
        }
    } else {
#pragma unroll
        for (int i = 0; i < 4; i++) {
            int rowb = m0 + (wm << 6) + (i << 4) + (q << 2);
#pragma unroll
            for (int jp = 0; jp < 4; jp += 2) {
                int brb = n0 + (wn << 6) + (jp << 4);
                int lcol = ((brb >> 5) << 4) + l15;
#pragma unroll
                for (int r = 0; r < 4; r++) {
                    float u = acc[i][jp][r], v = acc[i][jp + 1][r];
                    G[(size_t)(rowb + r) * 2048 + lcol] = f2bf(silu_f(u) * v);
                }
            }
        }
    }
}

// ---- merged stage-B GEMM, split-K=2, XCD-partitioned ----
__global__ __launch_bounds__(256) void gemm_B(
    const u16* __restrict__ H, const u16* __restrict__ G,
    const u16* __restrict__ W2b, const u16* __restrict__ S3b,
    const float* __restrict__ b2, const u16* __restrict__ X3h,
    u16* __restrict__ P0, u16* __restrict__ P1,
    float* __restrict__ Z0, float* __restrict__ Z1,
    const int* __restrict__ tileexp, const int* __restrict__ ntiles) {
    __shared__ u16 LDS[16384];
    int xcd = blockIdx.x & 7, ws = blockIdx.x >> 3;   // ws in [0,112)
    const u16 *Ab, *Bb; int mt, nt, kc, lda, kbeg, np, e = 0; bool routed;
    if (ws < 80) {
        routed = true;
        mt = xcd * 5 + (ws >> 4);
        int r = ws & 15; nt = r & 7; kc = r >> 3;
        if (mt >= ntiles[0]) return;
        e = tileexp[mt];
        Ab = H; Bb = W2b + ((size_t)e << 20); lda = 1024; kbeg = kc << 9; np = 8;
    } else {
        routed = false; int s = ws - 80;
        kc = s & 1; int s2 = s >> 1;
        mt = ((xcd >> 1) << 2) + (s2 >> 2);
        nt = ((xcd & 1) << 2) + (s2 & 3);
        Ab = G; Bb = S3b; lda = 2048; kbeg = kc << 10; np = 16;
    }
    int m0 = mt * 128, n0 = nt * 128;
    GEMM_PRE();

    KLOOP(np, Ab, Bb, lda, kbeg);

    if (routed) {
        u16* Pk = kc ? P1 : P0;
#pragma unroll
        for (int i = 0; i < 4; i++) {
            int rowb = m0 + (wm << 6) + (i << 4) + (q << 2);
#pragma unroll
            for (int j = 0; j < 4; j++) {
                int col = n0 + (wn << 6) + (j << 4) + l15;
#pragma unroll
                for (int r = 0; r < 4; r++) {
                    int rw = rowb + r;
                    float v = acc[i][j][r] + (kc == 0 ? b2[e * 1024 + col] : 0.f);
                    float pv = v * bf2f(X3h[(size_t)rw * 1024 + col]);
                    Pk[(size_t)rw * 1024 + col] = f2bf(pv);
                }
            }
        }
    } else {
        float* Zk = kc ? Z1 : Z0;
#pragma unroll
        for (int i = 0; i < 4; i++) {
            int rowb = m0 + (wm << 6) + (i << 4) + (q << 2);
#pragma unroll
            for (int j = 0; j < 4; j++) {
                int col = n0 + (wn << 6) + (j << 4) + l15;
#pragma unroll
                for (int r = 0; r < 4; r++)
                    Zk[(size_t)(rowb + r) * 1024 + col] = acc[i][j][r];
            }
        }
    }
}

__global__ void final_k(const float* __restrict__ Z0, const float* __restrict__ Z1,
                        const u16* __restrict__ P0, const u16* __restrict__ P1,
                        const int* __restrict__ slot_of, float* __restrict__ out) {
    int i = blockIdx.x * 256 + threadIdx.x;
    int t = i >> 8, c4 = i & 255;
    int s0 = slot_of[2 * t], s1 = slot_of[2 * t + 1];
    float4 z0 = ((const float4*)Z0)[(size_t)t * 256 + c4];
    float4 z1 = ((const float4*)Z1)[(size_t)t * 256 + c4];
    ushort4 a0 = ((const ushort4*)P0)[(size_t)s0 * 256 + c4];
    ushort4 a1 = ((const ushort4*)P1)[(size_t)s0 * 256 + c4];
    ushort4 c0 = ((const ushort4*)P0)[(size_t)s1 * 256 + c4];
    ushort4 c1 = ((const ushort4*)P1)[(size_t)s1 * 256 + c4];
    float4 o;
    o.x = z0.x + z1.x + bf2f(a0.x) + bf2f(a1.x) + bf2f(c0.x) + bf2f(c1.x);
    o.y = z0.y + z1.y + bf2f(a0.y) + bf2f(a1.y) + bf2f(c0.y) + bf2f(c1.y);
    o.z = z0.z + z1.z + bf2f(a0.z) + bf2f(a1.z) + bf2f(c0.z) + bf2f(c1.z);
    o.w = z0.w + z1.w + bf2f(a0.w) + bf2f(a1.w) + bf2f(c0.w) + bf2f(c1.w);
    ((float4*)out)[(size_t)t * 256 + c4] = o;
}

extern "C" void kernel_launch(void* const* d_in, const int* in_sizes, int n_in,
                              void* d_out, int out_size, void* d_ws, size_t ws_size,
                              hipStream_t stream) {
    const float* x   = (const float*)d_in[0];
    const float* gw  = (const float*)d_in[1];
    const float* w1  = (const float*)d_in[2];
    const float* b1  = (const float*)d_in[3];
    const float* w2  = (const float*)d_in[4];
    const float* b2  = (const float*)d_in[5];
    const float* w3  = (const float*)d_in[6];
    const float* b3  = (const float*)d_in[7];
    const float* sw1 = (const float*)d_in[8];
    const float* sw2 = (const float*)d_in[9];
    const float* sw3 = (const float*)d_in[10];
    float* out = (float*)d_out;

    char* p = (char*)d_ws;
    int* ntiles  = (int*)(p + 192);
    int* tileexp = (int*)(p + 256);
    size_t off = 4096;
    u16*   XS      = (u16*)(p + off);   off += (size_t)MAXROWS * 1024 * 2;
    int*   idxA    = (int*)(p + off);   off += 16384;
    float* wA      = (float*)(p + off); off += 16384;
    int*   slot_of = (int*)(p + off);   off += 16384;
    u16*   H       = (u16*)(p + off);   off += (size_t)MAXROWS * 1024 * 2;
    u16*   X3h     = (u16*)(p + off);   off += (size_t)MAXROWS * 1024 * 2;
    u16*   P0      = (u16*)(p + off);   off += (size_t)MAXROWS * 1024 * 2;
    u16*   P1      = (u16*)(p + off);   off += (size_t)MAXROWS * 1024 * 2;
    float* Z0      = (float*)(p + off); off += (size_t)2048 * 1024 * 4;
    float* Z1      = (float*)(p + off); off += (size_t)2048 * 1024 * 4;
    u16*   W13     = (u16*)(p + off);   off += (size_t)8 * 2048 * 1024 * 2;
    u16*   W2b     = (u16*)(p + off);   off += (size_t)8 * 1024 * 1024 * 2;
    u16*   S12     = (u16*)(p + off);   off += (size_t)4096 * 1024 * 2;
    u16*   S3b     = (u16*)(p + off);   off += (size_t)1024 * 2048 * 2;
    u16*   Xb      = (u16*)(p + off);   off += (size_t)2048 * 1024 * 2;
    u16*   G       = (u16*)(p + off);   off += (size_t)2048 * 2048 * 2;

    conv_gate<<<33280, 256, 0, stream>>>(w1, w2, w3, sw1, sw2, sw3, x, gw,
                                         W13, W2b, S12, S3b, Xb, idxA, wA);
    rank_k<<<1, 64, 0, stream>>>(idxA, tileexp, ntiles, slot_of);
    build_xs<<<4096, 256, 0, stream>>>(x, wA, slot_of, XS);

    gemm_A<<<1152, 256, 0, stream>>>(XS, Xb, W13, S12, b1, b3, H, X3h, G,
                                     tileexp, ntiles);
    gemm_B<<<896, 256, 0, stream>>>(H, G, W2b, S3b, b2, X3h, P0, P1, Z0, Z1,
                                    tileexp, ntiles);
    final_k<<<2048, 256, 0, stream>>>(Z0, Z1, P0, P1, slot_of, out);
}